// Round 9
// baseline (559.384 us; speedup 1.0000x reference)
//
#include <hip/hip_runtime.h>

#define NUSERS 250000
#define NITEMS 250000
#define NNODES 500000
#define NEDGES 1200000
#define NBLK   1954          // ceil(NNODES/256)
#define NGROUPS (NNODES/16)  // 31250
#define NCHUNKS (NNODES/8)   // 62500

typedef _Float16 half_t;
typedef _Float16 half8 __attribute__((ext_vector_type(8)));
typedef _Float16 half4 __attribute__((ext_vector_type(4)));
typedef float    f32x4 __attribute__((ext_vector_type(4)));

// ---------------- degree / normalization ----------------

__global__ void k_zero_deg(int* __restrict__ deg) {
    int n = blockIdx.x * blockDim.x + threadIdx.x;
    if (n < NNODES) deg[n] = 0;
}

__global__ void k_count_deg(const int* __restrict__ dst, int* __restrict__ deg) {
    int e = blockIdx.x * blockDim.x + threadIdx.x;
    if (e < NEDGES) atomicAdd(&deg[dst[e]], 1);
}

__global__ void k_dinv(const int* __restrict__ deg, float* __restrict__ dinv) {
    int n = blockIdx.x * blockDim.x + threadIdx.x;
    if (n < NNODES) dinv[n] = 1.0f / sqrtf((float)(deg[n] + 1));
}

// ---------------- CSR build ----------------

__global__ __launch_bounds__(256) void k_block_sums(const int* __restrict__ deg,
                                                    int* __restrict__ partials) {
    __shared__ int sm[256];
    int t = threadIdx.x;
    int n = blockIdx.x * 256 + t;
    int v = (n < NNODES) ? deg[n] : 0;
    sm[t] = v; __syncthreads();
    for (int d = 128; d > 0; d >>= 1) {
        if (t < d) sm[t] += sm[t + d];
        __syncthreads();
    }
    if (t == 0) partials[blockIdx.x] = sm[0];
}

__global__ __launch_bounds__(256) void k_scan_partials(int* __restrict__ partials) {
    __shared__ int sm[256];
    int t = threadIdx.x;
    int v[8]; int s = 0;
#pragma unroll
    for (int i = 0; i < 8; ++i) {
        int idx = t * 8 + i;
        v[i] = (idx < NBLK) ? partials[idx] : 0;
        s += v[i];
    }
    sm[t] = s; __syncthreads();
    for (int d = 1; d < 256; d <<= 1) {
        int x = (t >= d) ? sm[t - d] : 0;
        __syncthreads();
        sm[t] += x;
        __syncthreads();
    }
    int run = sm[t] - s;
#pragma unroll
    for (int i = 0; i < 8; ++i) {
        int idx = t * 8 + i;
        if (idx < NBLK) partials[idx] = run;
        run += v[i];
    }
}

__global__ __launch_bounds__(256) void k_scan_blocks(const int* __restrict__ partials,
                                                     int* __restrict__ degcursor,
                                                     int* __restrict__ offsets) {
    __shared__ int sm[256];
    int t = threadIdx.x;
    int n = blockIdx.x * 256 + t;
    int v = (n < NNODES) ? degcursor[n] : 0;
    sm[t] = v; __syncthreads();
    for (int d = 1; d < 256; d <<= 1) {
        int x = (t >= d) ? sm[t - d] : 0;
        __syncthreads();
        sm[t] += x;
        __syncthreads();
    }
    int off = partials[blockIdx.x] + sm[t] - v;
    if (n < NNODES) {
        offsets[n]   = off;
        degcursor[n] = off;
        if (n == NNODES - 1) offsets[NNODES] = off + v;
    }
}

// pack (src<<3) | (dst&7): src < 2^19 -> fits in 22 bits
__global__ void k_place(const int* __restrict__ src, const int* __restrict__ dst,
                        int* __restrict__ cursor, int* __restrict__ csr_pk) {
    int e = blockIdx.x * blockDim.x + threadIdx.x;
    if (e < NEDGES) {
        int d = dst[e];
        int pos = atomicAdd(&cursor[d], 1);
        csr_pk[pos] = (src[e] << 3) | (d & 7);
    }
}

// ---------------- MFMA helpers ----------------
// A: lane holds row (lane&15), k = 32q + 8*(lane>>4) + j
// B: lane holds col-slot (lane&15), same k formula; out-feature = 4*(lane&15)+c
// C/D: node = n0 + (lane>>4)*4 + r, feat = 4*(lane&15)+c

__device__ __forceinline__ void build_bfrags(const float* __restrict__ W,
                                             int lg, int cl, half8 bf[2][4]) {
#pragma unroll
    for (int q = 0; q < 2; ++q)
#pragma unroll
        for (int c = 0; c < 4; ++c) {
            half8 v;
#pragma unroll
            for (int j = 0; j < 8; ++j)
                v[j] = (half_t)W[(32 * q + 8 * lg + j) * 64 + 4 * cl + c];
            bf[q][c] = v;
        }
}

// ---------------- k_mm1: g1 = (gather(emb) @ W1) * dinv  [fp16 out] ----------------

__global__ __launch_bounds__(256) void k_mm1(
    const float* __restrict__ user_table, const float* __restrict__ item_table,
    const int* __restrict__ uid, const int* __restrict__ iid,
    const float* __restrict__ W1, const float* __restrict__ dinv,
    half_t* __restrict__ g)
{
    const int lane = threadIdx.x & 63;
    const int lg = lane >> 4, cl = lane & 15;
    const int wid = blockIdx.x * (blockDim.x >> 6) + (threadIdx.x >> 6);
    const int nw  = gridDim.x * (blockDim.x >> 6);

    half8 bf[2][4];
    build_bfrags(W1, lg, cl, bf);
    const f32x4 zacc = {0.f, 0.f, 0.f, 0.f};

    for (int t = wid; t < NGROUPS; t += nw) {
        const int n0 = t * 16;
        const int na = n0 + cl;                    // NUSERS%16==0: tiles never straddle
        const float* p = (na < NUSERS)
            ? user_table + (size_t)uid[na] * 64
            : item_table + (size_t)iid[na - NUSERS] * 64;
        f32x4 u0 = *(const f32x4*)(p + 8 * lg);
        f32x4 u1 = *(const f32x4*)(p + 8 * lg + 4);
        f32x4 u2 = *(const f32x4*)(p + 8 * lg + 32);
        f32x4 u3 = *(const f32x4*)(p + 8 * lg + 36);
        half8 a0, a1;
#pragma unroll
        for (int j = 0; j < 4; ++j) {
            a0[j] = (half_t)u0[j]; a0[4 + j] = (half_t)u1[j];
            a1[j] = (half_t)u2[j]; a1[4 + j] = (half_t)u3[j];
        }
        f32x4 acc[4];
#pragma unroll
        for (int c = 0; c < 4; ++c) {
            acc[c] = __builtin_amdgcn_mfma_f32_16x16x32_f16(a0, bf[0][c], zacc, 0, 0, 0);
            acc[c] = __builtin_amdgcn_mfma_f32_16x16x32_f16(a1, bf[1][c], acc[c], 0, 0, 0);
        }
#pragma unroll
        for (int r = 0; r < 4; ++r) {
            const int nd = n0 + lg * 4 + r;
            const float dn = dinv[nd];
            half4 hv;
#pragma unroll
            for (int c = 0; c < 4; ++c) hv[c] = (half_t)(acc[c][r] * dn);
            *(half4*)(g + (size_t)nd * 64 + 4 * cl) = hv;
        }
    }
}

// ---------------- sorted merge-walk 8-node gather ----------------
// Chunk of 8 nodes owns contiguous CSR range off[n0]..off[n0+8], SORTED by
// destination. Walk edges with one running accumulator; destination changes
// are wave-uniform (scalar pipe via readfirstlane). Each node flushed exactly
// once; skipped nodes emit preloaded self values via cndmask-select tree.

template <class F>
__device__ __forceinline__ void gather_walk8(
    const int* __restrict__ off, const int* __restrict__ csr,
    const half_t* __restrict__ gin, const int n0, const int lane,
    F flush)
{
    const half_t* selfp = gin + (size_t)n0 * 64 + lane;
    const float s0 = (float)selfp[0],   s1 = (float)selfp[64];
    const float s2 = (float)selfp[128], s3 = (float)selfp[192];
    const float s4 = (float)selfp[256], s5 = (float)selfp[320];
    const float s6 = (float)selfp[384], s7 = (float)selfp[448];

    auto sel8 = [&](int k) -> float {
        return k < 4 ? (k < 2 ? (k == 0 ? s0 : s1) : (k == 2 ? s2 : s3))
                     : (k < 6 ? (k == 4 ? s4 : s5) : (k == 6 ? s6 : s7));
    };
    auto row = [&](int q) -> float {
        return (float)*(gin + (size_t)(q >> 3) * 64 + lane);
    };

    int e  = off[n0];
    const int en = off[n0 + 8];
    int cur = 0;
    float acc = s0;

    auto consume = [&](int q, float r) {
        const int qj = q & 7;
        if (qj != cur) {
            flush(cur, acc);
            for (++cur; cur < qj; ++cur) flush(cur, sel8(cur));
            acc = sel8(qj) + r;
        } else {
            acc += r;
        }
    };

    for (; e + 8 <= en; e += 8) {
        const int q0 = __builtin_amdgcn_readfirstlane(csr[e + 0]);
        const int q1 = __builtin_amdgcn_readfirstlane(csr[e + 1]);
        const int q2 = __builtin_amdgcn_readfirstlane(csr[e + 2]);
        const int q3 = __builtin_amdgcn_readfirstlane(csr[e + 3]);
        const int q4 = __builtin_amdgcn_readfirstlane(csr[e + 4]);
        const int q5 = __builtin_amdgcn_readfirstlane(csr[e + 5]);
        const int q6 = __builtin_amdgcn_readfirstlane(csr[e + 6]);
        const int q7 = __builtin_amdgcn_readfirstlane(csr[e + 7]);
        const float r0 = row(q0), r1 = row(q1), r2 = row(q2), r3 = row(q3);
        const float r4 = row(q4), r5 = row(q5), r6 = row(q6), r7 = row(q7);
        consume(q0, r0); consume(q1, r1); consume(q2, r2); consume(q3, r3);
        consume(q4, r4); consume(q5, r5); consume(q6, r6); consume(q7, r7);
    }
    for (; e < en; ++e) {
        const int q = __builtin_amdgcn_readfirstlane(csr[e]);
        const float r = row(q);
        consume(q, r);
    }
    flush(cur, acc);
    for (++cur; cur < 8; ++cur) flush(cur, sel8(cur));
}

// pure gather: s[n] = g[n] + sum_in g[src]   [fp16 out]
__global__ __launch_bounds__(256) void k_gather(
    const int* __restrict__ off, const int* __restrict__ csr,
    const half_t* __restrict__ gin, half_t* __restrict__ sout)
{
    const int lane = threadIdx.x & 63;
    const int wid = blockIdx.x * (blockDim.x >> 6) + (threadIdx.x >> 6);
    const int nw  = gridDim.x * (blockDim.x >> 6);

    for (int t = wid; t < NCHUNKS; t += nw) {
        const int n0 = t * 8;
        half_t* outp = sout + (size_t)n0 * 64 + lane;
        gather_walk8(off, csr, gin, n0, lane, [&](int j, float v) {
            outp[j * 64] = (half_t)v;
        });
    }
}

// ---------------- k_mm2: g2 = (relu(dinv*s + b1) @ W2) * dinv ----------------

__global__ __launch_bounds__(256) void k_mm2(
    const float* __restrict__ W2, const float* __restrict__ b1,
    const float* __restrict__ dinv,
    const half_t* __restrict__ s, half_t* __restrict__ g)
{
    const int lane = threadIdx.x & 63;
    const int lg = lane >> 4, cl = lane & 15;
    const int wid = blockIdx.x * (blockDim.x >> 6) + (threadIdx.x >> 6);
    const int nw  = gridDim.x * (blockDim.x >> 6);

    half8 bf[2][4];
    build_bfrags(W2, lg, cl, bf);
    float bias0[8], bias1[8];
#pragma unroll
    for (int j = 0; j < 8; ++j) {
        bias0[j] = b1[8 * lg + j];
        bias1[j] = b1[32 + 8 * lg + j];
    }
    const f32x4 zacc = {0.f, 0.f, 0.f, 0.f};

    for (int t = wid; t < NGROUPS; t += nw) {
        const int n0 = t * 16;
        const int na = n0 + cl;
        const float dna = dinv[na];
        half8 s0 = *(const half8*)(s + (size_t)na * 64 + 8 * lg);
        half8 s1 = *(const half8*)(s + (size_t)na * 64 + 32 + 8 * lg);
        half8 a0, a1;
#pragma unroll
        for (int j = 0; j < 8; ++j) {
            a0[j] = (half_t)fmaxf(fmaf(dna, (float)s0[j], bias0[j]), 0.0f);
            a1[j] = (half_t)fmaxf(fmaf(dna, (float)s1[j], bias1[j]), 0.0f);
        }
        f32x4 acc[4];
#pragma unroll
        for (int c = 0; c < 4; ++c) {
            acc[c] = __builtin_amdgcn_mfma_f32_16x16x32_f16(a0, bf[0][c], zacc, 0, 0, 0);
            acc[c] = __builtin_amdgcn_mfma_f32_16x16x32_f16(a1, bf[1][c], acc[c], 0, 0, 0);
        }
#pragma unroll
        for (int r = 0; r < 4; ++r) {
            const int nd = n0 + lg * 4 + r;
            const float dn = dinv[nd];
            half4 hv;
#pragma unroll
            for (int c = 0; c < 4; ++c) hv[c] = (half_t)(acc[c][r] * dn);
            *(half4*)(g + (size_t)nd * 64 + 4 * cl) = hv;
        }
    }
}

// ---------------- gather(g2) + relu + Wp-dot fused -> pscore ----------------

__global__ __launch_bounds__(256) void k_gather_ps(
    const int* __restrict__ off, const int* __restrict__ csr,
    const float* __restrict__ b2, const float* __restrict__ Wp,
    const float* __restrict__ dinv,
    const half_t* __restrict__ g2, float* __restrict__ pscore)
{
    const int lane = threadIdx.x & 63;
    const int wid = blockIdx.x * (blockDim.x >> 6) + (threadIdx.x >> 6);
    const int nw  = gridDim.x * (blockDim.x >> 6);
    const float bb  = b2[lane];
    const float wpu = Wp[lane];
    const float wpi = Wp[64 + lane];

    for (int t = wid; t < NCHUNKS; t += nw) {
        const int n0 = t * 8;
        const float* dvp = dinv + n0;
        const float d0 = dvp[0], d1 = dvp[1], d2 = dvp[2], d3 = dvp[3];
        const float d4 = dvp[4], d5 = dvp[5], d6 = dvp[6], d7 = dvp[7];
        auto seld = [&](int k) -> float {
            return k < 4 ? (k < 2 ? (k == 0 ? d0 : d1) : (k == 2 ? d2 : d3))
                         : (k < 6 ? (k == 4 ? d4 : d5) : (k == 6 ? d6 : d7));
        };
        const float wsel = (n0 < NUSERS) ? wpu : wpi;   // NUSERS%8==0: chunk uniform

        gather_walk8(off, csr, g2, n0, lane, [&](int j, float sum) {
            float x2 = fmaxf(fmaf(seld(j), sum, bb), 0.0f);
            float v = x2 * wsel;
#pragma unroll
            for (int o2 = 32; o2 > 0; o2 >>= 1) v += __shfl_xor(v, o2, 64);
            if (lane == 0) pscore[n0 + j] = v;
        });
    }
}

__global__ void k_pairs(const int* __restrict__ user_ids, const int* __restrict__ item_ids,
                        const float* __restrict__ pscore, const float* __restrict__ bp,
                        float* __restrict__ out)
{
    int b = blockIdx.x * blockDim.x + threadIdx.x;
    if (b < NUSERS)
        out[b] = pscore[user_ids[b]] + pscore[NUSERS + item_ids[b]] + bp[0];
}

// ---------------- launch ----------------
// Workspace layout (byte-exact):
//   deg/cursor :          0 ..   2,000,000   (reused as pscore after k_place)
//   dinv       :  2,000,000 ..   4,000,000
//   offsets    :  4,000,000 ..   6,000,004   (NNODES+1 ints)
//   partials   :  6,000,128 ..   6,007,944
//   csr_pk     :  6,008,000 ..  10,808,000
//   bufA       : 10,808,064 ..  74,808,064   (NNODES*64 fp16)  g1, then g2
//   bufB       : 74,808,064 .. 138,808,064   s1

extern "C" void kernel_launch(void* const* d_in, const int* in_sizes, int n_in,
                              void* d_out, int out_size, void* d_ws, size_t ws_size,
                              hipStream_t stream)
{
    const float* user_table = (const float*)d_in[0];
    const float* item_table = (const float*)d_in[1];
    const float* W1 = (const float*)d_in[2];
    const float* b1 = (const float*)d_in[3];
    const float* W2 = (const float*)d_in[4];
    const float* b2 = (const float*)d_in[5];
    const float* Wp = (const float*)d_in[6];
    const float* bp = (const float*)d_in[7];
    const int* edge = (const int*)d_in[8];
    const int* uid  = (const int*)d_in[9];
    const int* iid  = (const int*)d_in[10];
    float* out = (float*)d_out;

    const int* src = edge;
    const int* dst = edge + NEDGES;

    char* ws = (char*)d_ws;
    int*    deg      = (int*)   (ws + 0);
    float*  dinv     = (float*) (ws + 2000000);
    int*    offsets  = (int*)   (ws + 4000000);
    int*    partials = (int*)   (ws + 6000128);
    int*    csr_pk   = (int*)   (ws + 6008000);
    half_t* bufA     = (half_t*)(ws + 10808064);
    half_t* bufB     = (half_t*)(ws + 74808064);
    float*  pscore   = (float*) (ws + 0);        // aliases deg (dead after k_place)

    k_zero_deg     <<<NBLK, 256, 0, stream>>>(deg);
    k_count_deg    <<<(NEDGES + 255) / 256, 256, 0, stream>>>(dst, deg);
    k_dinv         <<<NBLK, 256, 0, stream>>>(deg, dinv);
    k_block_sums   <<<NBLK, 256, 0, stream>>>(deg, partials);
    k_scan_partials<<<1, 256, 0, stream>>>(partials);
    k_scan_blocks  <<<NBLK, 256, 0, stream>>>(partials, deg, offsets);
    k_place        <<<(NEDGES + 255) / 256, 256, 0, stream>>>(src, dst, deg, csr_pk);

    k_mm1      <<<2048, 256, 0, stream>>>(user_table, item_table, uid, iid, W1, dinv, bufA);
    k_gather   <<<2048, 256, 0, stream>>>(offsets, csr_pk, bufA, bufB);
    k_mm2      <<<2048, 256, 0, stream>>>(W2, b1, dinv, bufB, bufA);
    k_gather_ps<<<2048, 256, 0, stream>>>(offsets, csr_pk, b2, Wp, dinv, bufA, pscore);
    k_pairs    <<<(NUSERS + 255) / 256, 256, 0, stream>>>(uid, iid, pscore, bp, out);
}

// Round 10
// 379.254 us; speedup vs baseline: 1.4750x; 1.4750x over previous
//
#include <hip/hip_runtime.h>

#define NUSERS 250000
#define NITEMS 250000
#define NNODES 500000
#define NEDGES 1200000
#define NBLK   1954          // ceil(NNODES/256)
#define NGROUPS (NNODES/16)  // 31250
#define NCH4   (NNODES/4)    // 125000

typedef _Float16 half_t;
typedef _Float16 half8 __attribute__((ext_vector_type(8)));
typedef _Float16 half4 __attribute__((ext_vector_type(4)));
typedef _Float16 half2_t __attribute__((ext_vector_type(2)));
typedef float    f32x4 __attribute__((ext_vector_type(4)));
typedef float    f32x2 __attribute__((ext_vector_type(2)));

// ---------------- degree / normalization ----------------

__global__ void k_zero_deg(int* __restrict__ deg) {
    int n = blockIdx.x * blockDim.x + threadIdx.x;
    if (n < NNODES) deg[n] = 0;
}

__global__ void k_count_deg(const int* __restrict__ dst, int* __restrict__ deg) {
    int e = blockIdx.x * blockDim.x + threadIdx.x;
    if (e < NEDGES) atomicAdd(&deg[dst[e]], 1);
}

__global__ void k_dinv(const int* __restrict__ deg, float* __restrict__ dinv) {
    int n = blockIdx.x * blockDim.x + threadIdx.x;
    if (n < NNODES) dinv[n] = 1.0f / sqrtf((float)(deg[n] + 1));
}

// ---------------- CSR build ----------------

__global__ __launch_bounds__(256) void k_block_sums(const int* __restrict__ deg,
                                                    int* __restrict__ partials) {
    __shared__ int sm[256];
    int t = threadIdx.x;
    int n = blockIdx.x * 256 + t;
    int v = (n < NNODES) ? deg[n] : 0;
    sm[t] = v; __syncthreads();
    for (int d = 128; d > 0; d >>= 1) {
        if (t < d) sm[t] += sm[t + d];
        __syncthreads();
    }
    if (t == 0) partials[blockIdx.x] = sm[0];
}

__global__ __launch_bounds__(256) void k_scan_partials(int* __restrict__ partials) {
    __shared__ int sm[256];
    int t = threadIdx.x;
    int v[8]; int s = 0;
#pragma unroll
    for (int i = 0; i < 8; ++i) {
        int idx = t * 8 + i;
        v[i] = (idx < NBLK) ? partials[idx] : 0;
        s += v[i];
    }
    sm[t] = s; __syncthreads();
    for (int d = 1; d < 256; d <<= 1) {
        int x = (t >= d) ? sm[t - d] : 0;
        __syncthreads();
        sm[t] += x;
        __syncthreads();
    }
    int run = sm[t] - s;
#pragma unroll
    for (int i = 0; i < 8; ++i) {
        int idx = t * 8 + i;
        if (idx < NBLK) partials[idx] = run;
        run += v[i];
    }
}

__global__ __launch_bounds__(256) void k_scan_blocks(const int* __restrict__ partials,
                                                     int* __restrict__ degcursor,
                                                     int* __restrict__ offsets) {
    __shared__ int sm[256];
    int t = threadIdx.x;
    int n = blockIdx.x * 256 + t;
    int v = (n < NNODES) ? degcursor[n] : 0;
    sm[t] = v; __syncthreads();
    for (int d = 1; d < 256; d <<= 1) {
        int x = (t >= d) ? sm[t - d] : 0;
        __syncthreads();
        sm[t] += x;
        __syncthreads();
    }
    int off = partials[blockIdx.x] + sm[t] - v;
    if (n < NNODES) {
        offsets[n]   = off;
        degcursor[n] = off;
        if (n == NNODES - 1) offsets[NNODES] = off + v;
    }
}

// pack (src<<2) | (dst&3): src < 2^19 -> fits in 21 bits
__global__ void k_place(const int* __restrict__ src, const int* __restrict__ dst,
                        int* __restrict__ cursor, int* __restrict__ csr_pk) {
    int e = blockIdx.x * blockDim.x + threadIdx.x;
    if (e < NEDGES) {
        int d = dst[e];
        int pos = atomicAdd(&cursor[d], 1);
        csr_pk[pos] = (src[e] << 2) | (d & 3);
    }
}

// ---------------- MFMA helpers ----------------
// A: lane holds row (lane&15), k = 32q + 8*(lane>>4) + j
// B: lane holds col-slot (lane&15), same k formula; out-feature = 4*(lane&15)+c
// C/D: node = n0 + (lane>>4)*4 + r, feat = 4*(lane&15)+c

__device__ __forceinline__ void build_bfrags(const float* __restrict__ W,
                                             int lg, int cl, half8 bf[2][4]) {
#pragma unroll
    for (int q = 0; q < 2; ++q)
#pragma unroll
        for (int c = 0; c < 4; ++c) {
            half8 v;
#pragma unroll
            for (int j = 0; j < 8; ++j)
                v[j] = (half_t)W[(32 * q + 8 * lg + j) * 64 + 4 * cl + c];
            bf[q][c] = v;
        }
}

// ---------------- k_mm1: g1 = (gather(emb) @ W1) * dinv  [fp16 out] ----------------

__global__ __launch_bounds__(256) void k_mm1(
    const float* __restrict__ user_table, const float* __restrict__ item_table,
    const int* __restrict__ uid, const int* __restrict__ iid,
    const float* __restrict__ W1, const float* __restrict__ dinv,
    half_t* __restrict__ g)
{
    const int lane = threadIdx.x & 63;
    const int lg = lane >> 4, cl = lane & 15;
    const int wid = blockIdx.x * (blockDim.x >> 6) + (threadIdx.x >> 6);
    const int nw  = gridDim.x * (blockDim.x >> 6);

    half8 bf[2][4];
    build_bfrags(W1, lg, cl, bf);
    const f32x4 zacc = {0.f, 0.f, 0.f, 0.f};

    for (int t = wid; t < NGROUPS; t += nw) {
        const int n0 = t * 16;
        const int na = n0 + cl;                    // NUSERS%16==0: tiles never straddle
        const float* p = (na < NUSERS)
            ? user_table + (size_t)uid[na] * 64
            : item_table + (size_t)iid[na - NUSERS] * 64;
        f32x4 u0 = *(const f32x4*)(p + 8 * lg);
        f32x4 u1 = *(const f32x4*)(p + 8 * lg + 4);
        f32x4 u2 = *(const f32x4*)(p + 8 * lg + 32);
        f32x4 u3 = *(const f32x4*)(p + 8 * lg + 36);
        half8 a0, a1;
#pragma unroll
        for (int j = 0; j < 4; ++j) {
            a0[j] = (half_t)u0[j]; a0[4 + j] = (half_t)u1[j];
            a1[j] = (half_t)u2[j]; a1[4 + j] = (half_t)u3[j];
        }
        f32x4 acc[4];
#pragma unroll
        for (int c = 0; c < 4; ++c) {
            acc[c] = __builtin_amdgcn_mfma_f32_16x16x32_f16(a0, bf[0][c], zacc, 0, 0, 0);
            acc[c] = __builtin_amdgcn_mfma_f32_16x16x32_f16(a1, bf[1][c], acc[c], 0, 0, 0);
        }
#pragma unroll
        for (int r = 0; r < 4; ++r) {
            const int nd = n0 + lg * 4 + r;
            const float dn = dinv[nd];
            half4 hv;
#pragma unroll
            for (int c = 0; c < 4; ++c) hv[c] = (half_t)(acc[c][r] * dn);
            *(half4*)(g + (size_t)nd * 64 + 4 * cl) = hv;
        }
    }
}

// ---------------- half-wave 2-feature gather, 4-node chunks ----------------
// Lanes 0-31 and 32-63 each process one edge per step (2 edges in flight per
// wave step); each lane covers 2 fp16 features as f32x2. Halves are combined
// once per chunk via shfl_xor(32). All accumulators are named registers.

__device__ __forceinline__ f32x2 ldrow2(const half_t* __restrict__ gin,
                                        int node, int fo) {
    half2_t h = *(const half2_t*)(gin + (size_t)node * 64 + fo);
    f32x2 r; r.x = (float)h.x; r.y = (float)h.y; return r;
}

#define ROUTE(p, r, mv) {                                                   \
    const int jj_ = (p) & 3;                                                \
    float m0_ = (jj_ == 0) ? (mv) : 0.0f;                                   \
    float m1_ = (jj_ == 1) ? (mv) : 0.0f;                                   \
    float m2_ = (jj_ == 2) ? (mv) : 0.0f;                                   \
    float m3_ = (jj_ == 3) ? (mv) : 0.0f;                                   \
    s0.x = fmaf(m0_, (r).x, s0.x); s0.y = fmaf(m0_, (r).y, s0.y);           \
    s1.x = fmaf(m1_, (r).x, s1.x); s1.y = fmaf(m1_, (r).y, s1.y);           \
    s2.x = fmaf(m2_, (r).x, s2.x); s2.y = fmaf(m2_, (r).y, s2.y);           \
    s3.x = fmaf(m3_, (r).x, s3.x); s3.y = fmaf(m3_, (r).y, s3.y); }

#define GATHER4_BODY(gin)                                                   \
    f32x2 s0, s1, s2, s3;                                                   \
    {                                                                       \
        const f32x2 z = {0.f, 0.f};                                         \
        f32x2 a0 = ldrow2(gin, n0 + 0, fo);                                 \
        f32x2 a1 = ldrow2(gin, n0 + 1, fo);                                 \
        f32x2 a2 = ldrow2(gin, n0 + 2, fo);                                 \
        f32x2 a3 = ldrow2(gin, n0 + 3, fo);                                 \
        s0 = hf ? z : a0;  s1 = hf ? z : a1;                                \
        s2 = hf ? z : a2;  s3 = hf ? z : a3;                                \
    }                                                                       \
    {                                                                       \
        int e = off[n0];                                                    \
        const int en = off[n0 + 4];                                         \
        const int bo = hf << 2;                                             \
        for (; e < en; e += 8) {                                            \
            const int i0 = e + bo;                                          \
            const bool v0 = i0 + 0 < en, v1 = i0 + 1 < en;                  \
            const bool v2 = i0 + 2 < en, v3 = i0 + 3 < en;                  \
            const int p0 = csr[v0 ? i0 + 0 : 0];                            \
            const int p1 = csr[v1 ? i0 + 1 : 0];                            \
            const int p2 = csr[v2 ? i0 + 2 : 0];                            \
            const int p3 = csr[v3 ? i0 + 3 : 0];                            \
            const f32x2 r0 = ldrow2(gin, p0 >> 2, fo);                      \
            const f32x2 r1 = ldrow2(gin, p1 >> 2, fo);                      \
            const f32x2 r2 = ldrow2(gin, p2 >> 2, fo);                      \
            const f32x2 r3 = ldrow2(gin, p3 >> 2, fo);                      \
            const float mv0 = v0 ? 1.0f : 0.0f;                             \
            const float mv1 = v1 ? 1.0f : 0.0f;                             \
            const float mv2 = v2 ? 1.0f : 0.0f;                             \
            const float mv3 = v3 ? 1.0f : 0.0f;                             \
            ROUTE(p0, r0, mv0) ROUTE(p1, r1, mv1)                           \
            ROUTE(p2, r2, mv2) ROUTE(p3, r3, mv3)                           \
        }                                                                   \
    }                                                                       \
    f32x2 c0, c1, c2, c3;                                                   \
    c0.x = s0.x + __shfl_xor(s0.x, 32, 64); c0.y = s0.y + __shfl_xor(s0.y, 32, 64); \
    c1.x = s1.x + __shfl_xor(s1.x, 32, 64); c1.y = s1.y + __shfl_xor(s1.y, 32, 64); \
    c2.x = s2.x + __shfl_xor(s2.x, 32, 64); c2.y = s2.y + __shfl_xor(s2.y, 32, 64); \
    c3.x = s3.x + __shfl_xor(s3.x, 32, 64); c3.y = s3.y + __shfl_xor(s3.y, 32, 64);

// pure gather: s[n] = g[n] + sum_in g[src]   [fp16 out]
__global__ __launch_bounds__(256) void k_gather(
    const int* __restrict__ off, const int* __restrict__ csr,
    const half_t* __restrict__ gin, half_t* __restrict__ sout)
{
    const int lane = threadIdx.x & 63;
    const int hf = lane >> 5;
    const int fo = (lane & 31) * 2;
    const int wid = blockIdx.x * (blockDim.x >> 6) + (threadIdx.x >> 6);
    const int nw  = gridDim.x * (blockDim.x >> 6);

    for (int t = wid; t < NCH4; t += nw) {
        const int n0 = t * 4;
        GATHER4_BODY(gin)
        // half h stores rows {2h, 2h+1} (both halves hold identical combined sums)
        const f32x2 cA = hf ? c2 : c0;
        const f32x2 cB = hf ? c3 : c1;
        const int jA = 2 * hf, jB = 2 * hf + 1;
        half2_t hA; hA.x = (half_t)cA.x; hA.y = (half_t)cA.y;
        half2_t hB; hB.x = (half_t)cB.x; hB.y = (half_t)cB.y;
        *(half2_t*)(sout + (size_t)(n0 + jA) * 64 + fo) = hA;
        *(half2_t*)(sout + (size_t)(n0 + jB) * 64 + fo) = hB;
    }
}

// ---------------- k_mm2: g2 = (relu(dinv*s + b1) @ W2) * dinv ----------------

__global__ __launch_bounds__(256) void k_mm2(
    const float* __restrict__ W2, const float* __restrict__ b1,
    const float* __restrict__ dinv,
    const half_t* __restrict__ s, half_t* __restrict__ g)
{
    const int lane = threadIdx.x & 63;
    const int lg = lane >> 4, cl = lane & 15;
    const int wid = blockIdx.x * (blockDim.x >> 6) + (threadIdx.x >> 6);
    const int nw  = gridDim.x * (blockDim.x >> 6);

    half8 bf[2][4];
    build_bfrags(W2, lg, cl, bf);
    float bias0[8], bias1[8];
#pragma unroll
    for (int j = 0; j < 8; ++j) {
        bias0[j] = b1[8 * lg + j];
        bias1[j] = b1[32 + 8 * lg + j];
    }
    const f32x4 zacc = {0.f, 0.f, 0.f, 0.f};

    for (int t = wid; t < NGROUPS; t += nw) {
        const int n0 = t * 16;
        const int na = n0 + cl;
        const float dna = dinv[na];
        half8 s0 = *(const half8*)(s + (size_t)na * 64 + 8 * lg);
        half8 s1 = *(const half8*)(s + (size_t)na * 64 + 32 + 8 * lg);
        half8 a0, a1;
#pragma unroll
        for (int j = 0; j < 8; ++j) {
            a0[j] = (half_t)fmaxf(fmaf(dna, (float)s0[j], bias0[j]), 0.0f);
            a1[j] = (half_t)fmaxf(fmaf(dna, (float)s1[j], bias1[j]), 0.0f);
        }
        f32x4 acc[4];
#pragma unroll
        for (int c = 0; c < 4; ++c) {
            acc[c] = __builtin_amdgcn_mfma_f32_16x16x32_f16(a0, bf[0][c], zacc, 0, 0, 0);
            acc[c] = __builtin_amdgcn_mfma_f32_16x16x32_f16(a1, bf[1][c], acc[c], 0, 0, 0);
        }
#pragma unroll
        for (int r = 0; r < 4; ++r) {
            const int nd = n0 + lg * 4 + r;
            const float dn = dinv[nd];
            half4 hv;
#pragma unroll
            for (int c = 0; c < 4; ++c) hv[c] = (half_t)(acc[c][r] * dn);
            *(half4*)(g + (size_t)nd * 64 + 4 * cl) = hv;
        }
    }
}

// ---------------- gather(g2) + relu + Wp-dot fused -> pscore ----------------

__global__ __launch_bounds__(256) void k_gather_ps(
    const int* __restrict__ off, const int* __restrict__ csr,
    const float* __restrict__ b2, const float* __restrict__ Wp,
    const float* __restrict__ dinv,
    const half_t* __restrict__ g2, float* __restrict__ pscore)
{
    const int lane = threadIdx.x & 63;
    const int hf = lane >> 5;
    const int fo = (lane & 31) * 2;
    const int wid = blockIdx.x * (blockDim.x >> 6) + (threadIdx.x >> 6);
    const int nw  = gridDim.x * (blockDim.x >> 6);

    f32x2 bb2;  bb2.x  = b2[fo];      bb2.y  = b2[fo + 1];
    f32x2 wpu2; wpu2.x = Wp[fo];      wpu2.y = Wp[fo + 1];
    f32x2 wpi2; wpi2.x = Wp[64 + fo]; wpi2.y = Wp[64 + fo + 1];

    for (int t = wid; t < NCH4; t += nw) {
        const int n0 = t * 4;
        GATHER4_BODY(g2)

        const f32x2 wsel = (n0 < NUSERS) ? wpu2 : wpi2;   // NUSERS%4==0: chunk uniform
#define PS_FLUSH(J, CJ) {                                                   \
        const float dn_ = dinv[n0 + (J)];                                   \
        float xx_ = fmaxf(fmaf(dn_, (CJ).x, bb2.x), 0.0f) * wsel.x;         \
        float xy_ = fmaxf(fmaf(dn_, (CJ).y, bb2.y), 0.0f) * wsel.y;         \
        float t_ = xx_ + xy_;                                               \
        t_ += __shfl_xor(t_, 1, 64);  t_ += __shfl_xor(t_, 2, 64);          \
        t_ += __shfl_xor(t_, 4, 64);  t_ += __shfl_xor(t_, 8, 64);          \
        t_ += __shfl_xor(t_, 16, 64);                                       \
        if (lane == 0) pscore[n0 + (J)] = t_; }
        PS_FLUSH(0, c0) PS_FLUSH(1, c1) PS_FLUSH(2, c2) PS_FLUSH(3, c3)
#undef PS_FLUSH
    }
}

__global__ void k_pairs(const int* __restrict__ user_ids, const int* __restrict__ item_ids,
                        const float* __restrict__ pscore, const float* __restrict__ bp,
                        float* __restrict__ out)
{
    int b = blockIdx.x * blockDim.x + threadIdx.x;
    if (b < NUSERS)
        out[b] = pscore[user_ids[b]] + pscore[NUSERS + item_ids[b]] + bp[0];
}

// ---------------- launch ----------------
// Workspace layout (byte-exact):
//   deg/cursor :          0 ..   2,000,000   (reused as pscore after k_place)
//   dinv       :  2,000,000 ..   4,000,000
//   offsets    :  4,000,000 ..   6,000,004   (NNODES+1 ints)
//   partials   :  6,000,128 ..   6,007,944
//   csr_pk     :  6,008,000 ..  10,808,000
//   bufA       : 10,808,064 ..  74,808,064   (NNODES*64 fp16)  g1, then g2
//   bufB       : 74,808,064 .. 138,808,064   s1

extern "C" void kernel_launch(void* const* d_in, const int* in_sizes, int n_in,
                              void* d_out, int out_size, void* d_ws, size_t ws_size,
                              hipStream_t stream)
{
    const float* user_table = (const float*)d_in[0];
    const float* item_table = (const float*)d_in[1];
    const float* W1 = (const float*)d_in[2];
    const float* b1 = (const float*)d_in[3];
    const float* W2 = (const float*)d_in[4];
    const float* b2 = (const float*)d_in[5];
    const float* Wp = (const float*)d_in[6];
    const float* bp = (const float*)d_in[7];
    const int* edge = (const int*)d_in[8];
    const int* uid  = (const int*)d_in[9];
    const int* iid  = (const int*)d_in[10];
    float* out = (float*)d_out;

    const int* src = edge;
    const int* dst = edge + NEDGES;

    char* ws = (char*)d_ws;
    int*    deg      = (int*)   (ws + 0);
    float*  dinv     = (float*) (ws + 2000000);
    int*    offsets  = (int*)   (ws + 4000000);
    int*    partials = (int*)   (ws + 6000128);
    int*    csr_pk   = (int*)   (ws + 6008000);
    half_t* bufA     = (half_t*)(ws + 10808064);
    half_t* bufB     = (half_t*)(ws + 74808064);
    float*  pscore   = (float*) (ws + 0);        // aliases deg (dead after k_place)

    k_zero_deg     <<<NBLK, 256, 0, stream>>>(deg);
    k_count_deg    <<<(NEDGES + 255) / 256, 256, 0, stream>>>(dst, deg);
    k_dinv         <<<NBLK, 256, 0, stream>>>(deg, dinv);
    k_block_sums   <<<NBLK, 256, 0, stream>>>(deg, partials);
    k_scan_partials<<<1, 256, 0, stream>>>(partials);
    k_scan_blocks  <<<NBLK, 256, 0, stream>>>(partials, deg, offsets);
    k_place        <<<(NEDGES + 255) / 256, 256, 0, stream>>>(src, dst, deg, csr_pk);

    k_mm1      <<<2048, 256, 0, stream>>>(user_table, item_table, uid, iid, W1, dinv, bufA);
    k_gather   <<<2048, 256, 0, stream>>>(offsets, csr_pk, bufA, bufB);
    k_mm2      <<<2048, 256, 0, stream>>>(W2, b1, dinv, bufB, bufA);
    k_gather_ps<<<2048, 256, 0, stream>>>(offsets, csr_pk, b2, Wp, dinv, bufA, pscore);
    k_pairs    <<<(NUSERS + 255) / 256, 256, 0, stream>>>(uid, iid, pscore, bp, out);
}

// Round 11
// 303.625 us; speedup vs baseline: 1.8423x; 1.2491x over previous
//
#include <hip/hip_runtime.h>

#define NUSERS 250000
#define NITEMS 250000
#define NNODES 500000
#define NEDGES 1200000
#define NBLK   1954          // ceil(NNODES/256)
#define NGROUPS (NNODES/16)  // 31250
#define NCH8   (NNODES/8)    // 62500

typedef _Float16 half_t;
typedef _Float16 half8 __attribute__((ext_vector_type(8)));
typedef _Float16 half4 __attribute__((ext_vector_type(4)));
typedef float    f32x4 __attribute__((ext_vector_type(4)));

// ---------------- degree / normalization ----------------

__global__ void k_zero_deg(int* __restrict__ deg) {
    int n = blockIdx.x * blockDim.x + threadIdx.x;
    if (n < NNODES) deg[n] = 0;
}

__global__ void k_count_deg(const int* __restrict__ dst, int* __restrict__ deg) {
    int e = blockIdx.x * blockDim.x + threadIdx.x;
    if (e < NEDGES) atomicAdd(&deg[dst[e]], 1);
}

__global__ void k_dinv(const int* __restrict__ deg, float* __restrict__ dinv) {
    int n = blockIdx.x * blockDim.x + threadIdx.x;
    if (n < NNODES) dinv[n] = 1.0f / sqrtf((float)(deg[n] + 1));
}

// ---------------- CSR build ----------------

__global__ __launch_bounds__(256) void k_block_sums(const int* __restrict__ deg,
                                                    int* __restrict__ partials) {
    __shared__ int sm[256];
    int t = threadIdx.x;
    int n = blockIdx.x * 256 + t;
    int v = (n < NNODES) ? deg[n] : 0;
    sm[t] = v; __syncthreads();
    for (int d = 128; d > 0; d >>= 1) {
        if (t < d) sm[t] += sm[t + d];
        __syncthreads();
    }
    if (t == 0) partials[blockIdx.x] = sm[0];
}

__global__ __launch_bounds__(256) void k_scan_partials(int* __restrict__ partials) {
    __shared__ int sm[256];
    int t = threadIdx.x;
    int v[8]; int s = 0;
#pragma unroll
    for (int i = 0; i < 8; ++i) {
        int idx = t * 8 + i;
        v[i] = (idx < NBLK) ? partials[idx] : 0;
        s += v[i];
    }
    sm[t] = s; __syncthreads();
    for (int d = 1; d < 256; d <<= 1) {
        int x = (t >= d) ? sm[t - d] : 0;
        __syncthreads();
        sm[t] += x;
        __syncthreads();
    }
    int run = sm[t] - s;
#pragma unroll
    for (int i = 0; i < 8; ++i) {
        int idx = t * 8 + i;
        if (idx < NBLK) partials[idx] = run;
        run += v[i];
    }
}

__global__ __launch_bounds__(256) void k_scan_blocks(const int* __restrict__ partials,
                                                     int* __restrict__ degcursor,
                                                     int* __restrict__ offsets) {
    __shared__ int sm[256];
    int t = threadIdx.x;
    int n = blockIdx.x * 256 + t;
    int v = (n < NNODES) ? degcursor[n] : 0;
    sm[t] = v; __syncthreads();
    for (int d = 1; d < 256; d <<= 1) {
        int x = (t >= d) ? sm[t - d] : 0;
        __syncthreads();
        sm[t] += x;
        __syncthreads();
    }
    int off = partials[blockIdx.x] + sm[t] - v;
    if (n < NNODES) {
        offsets[n]   = off;
        degcursor[n] = off;
        if (n == NNODES - 1) offsets[NNODES] = off + v;
    }
}

__global__ void k_place(const int* __restrict__ src, const int* __restrict__ dst,
                        int* __restrict__ cursor, int* __restrict__ csr_src) {
    int e = blockIdx.x * blockDim.x + threadIdx.x;
    if (e < NEDGES) {
        int pos = atomicAdd(&cursor[dst[e]], 1);
        csr_src[pos] = src[e];
    }
}

// ---------------- MFMA helpers ----------------
// A: lane holds row (lane&15), k = 32q + 8*(lane>>4) + j
// B: lane holds col-slot (lane&15), same k formula; out-feature = 4*(lane&15)+c
// C/D: node = n0 + (lane>>4)*4 + r, feat = 4*(lane&15)+c

__device__ __forceinline__ void build_bfrags(const float* __restrict__ W,
                                             int lg, int cl, half8 bf[2][4]) {
#pragma unroll
    for (int q = 0; q < 2; ++q)
#pragma unroll
        for (int c = 0; c < 4; ++c) {
            half8 v;
#pragma unroll
            for (int j = 0; j < 8; ++j)
                v[j] = (half_t)W[(32 * q + 8 * lg + j) * 64 + 4 * cl + c];
            bf[q][c] = v;
        }
}

// ---------------- k_mm1: g1 = (gather(emb) @ W1) * dinv  [fp16 out] ----------------

__global__ __launch_bounds__(256) void k_mm1(
    const float* __restrict__ user_table, const float* __restrict__ item_table,
    const int* __restrict__ uid, const int* __restrict__ iid,
    const float* __restrict__ W1, const float* __restrict__ dinv,
    half_t* __restrict__ g)
{
    const int lane = threadIdx.x & 63;
    const int lg = lane >> 4, cl = lane & 15;
    const int wid = blockIdx.x * (blockDim.x >> 6) + (threadIdx.x >> 6);
    const int nw  = gridDim.x * (blockDim.x >> 6);

    half8 bf[2][4];
    build_bfrags(W1, lg, cl, bf);
    const f32x4 zacc = {0.f, 0.f, 0.f, 0.f};

    for (int t = wid; t < NGROUPS; t += nw) {
        const int n0 = t * 16;
        const int na = n0 + cl;                    // NUSERS%16==0: tiles never straddle
        const float* p = (na < NUSERS)
            ? user_table + (size_t)uid[na] * 64
            : item_table + (size_t)iid[na - NUSERS] * 64;
        f32x4 u0 = *(const f32x4*)(p + 8 * lg);
        f32x4 u1 = *(const f32x4*)(p + 8 * lg + 4);
        f32x4 u2 = *(const f32x4*)(p + 8 * lg + 32);
        f32x4 u3 = *(const f32x4*)(p + 8 * lg + 36);
        half8 a0, a1;
#pragma unroll
        for (int j = 0; j < 4; ++j) {
            a0[j] = (half_t)u0[j]; a0[4 + j] = (half_t)u1[j];
            a1[j] = (half_t)u2[j]; a1[4 + j] = (half_t)u3[j];
        }
        f32x4 acc[4];
#pragma unroll
        for (int c = 0; c < 4; ++c) {
            acc[c] = __builtin_amdgcn_mfma_f32_16x16x32_f16(a0, bf[0][c], zacc, 0, 0, 0);
            acc[c] = __builtin_amdgcn_mfma_f32_16x16x32_f16(a1, bf[1][c], acc[c], 0, 0, 0);
        }
#pragma unroll
        for (int r = 0; r < 4; ++r) {
            const int nd = n0 + lg * 4 + r;
            const float dn = dinv[nd];
            half4 hv;
#pragma unroll
            for (int c = 0; c < 4; ++c) hv[c] = (half_t)(acc[c][r] * dn);
            *(half4*)(g + (size_t)nd * 64 + 4 * cl) = hv;
        }
    }
}

// ---------------- group-per-node gather ----------------
// 8-lane group owns one node; lane covers 8 features (16 B). One wave step
// processes 8 edges with ONE row-load instruction. No routing, no cross-group
// reduction. Loop trip = wave-max degree; invalid steps are masked by a 0/1
// multiplier on a safe csr[0] load.

#define GATHER_G8(gin)                                                        \
    const int n  = n0 + gi;                                                   \
    const int eb = off[n];                                                    \
    const int deg = off[n + 1] - eb;                                          \
    float acc0, acc1, acc2, acc3, acc4, acc5, acc6, acc7;                     \
    {                                                                         \
        half8 sv = *(const half8*)(gin + (size_t)n * 64 + sub * 8);           \
        acc0 = (float)sv[0]; acc1 = (float)sv[1];                             \
        acc2 = (float)sv[2]; acc3 = (float)sv[3];                             \
        acc4 = (float)sv[4]; acc5 = (float)sv[5];                             \
        acc6 = (float)sv[6]; acc7 = (float)sv[7];                             \
    }                                                                         \
    int md = deg;                                                             \
    md = max(md, __shfl_xor(md, 8, 64));                                      \
    md = max(md, __shfl_xor(md, 16, 64));                                     \
    md = max(md, __shfl_xor(md, 32, 64));                                     \
    for (int sstep = 0; sstep < md; sstep += 2) {                             \
        const bool v0 = sstep < deg, v1 = sstep + 1 < deg;                    \
        const int p0 = csr[v0 ? eb + sstep : 0];                              \
        const int p1 = csr[v1 ? eb + sstep + 1 : 0];                          \
        const half8 r0 = *(const half8*)(gin + (size_t)p0 * 64 + sub * 8);    \
        const half8 r1 = *(const half8*)(gin + (size_t)p1 * 64 + sub * 8);    \
        const float m0 = v0 ? 1.0f : 0.0f;                                    \
        const float m1 = v1 ? 1.0f : 0.0f;                                    \
        acc0 = fmaf(m0, (float)r0[0], acc0); acc1 = fmaf(m0, (float)r0[1], acc1); \
        acc2 = fmaf(m0, (float)r0[2], acc2); acc3 = fmaf(m0, (float)r0[3], acc3); \
        acc4 = fmaf(m0, (float)r0[4], acc4); acc5 = fmaf(m0, (float)r0[5], acc5); \
        acc6 = fmaf(m0, (float)r0[6], acc6); acc7 = fmaf(m0, (float)r0[7], acc7); \
        acc0 = fmaf(m1, (float)r1[0], acc0); acc1 = fmaf(m1, (float)r1[1], acc1); \
        acc2 = fmaf(m1, (float)r1[2], acc2); acc3 = fmaf(m1, (float)r1[3], acc3); \
        acc4 = fmaf(m1, (float)r1[4], acc4); acc5 = fmaf(m1, (float)r1[5], acc5); \
        acc6 = fmaf(m1, (float)r1[6], acc6); acc7 = fmaf(m1, (float)r1[7], acc7); \
    }

// pure gather: s[n] = g[n] + sum_in g[src]   [fp16 out]
__global__ __launch_bounds__(256) void k_gather(
    const int* __restrict__ off, const int* __restrict__ csr,
    const half_t* __restrict__ gin, half_t* __restrict__ sout)
{
    const int lane = threadIdx.x & 63;
    const int gi = lane >> 3;       // group = node slot 0..7
    const int sub = lane & 7;       // feature octet
    const int wid = blockIdx.x * (blockDim.x >> 6) + (threadIdx.x >> 6);
    const int nw  = gridDim.x * (blockDim.x >> 6);

    for (int t = wid; t < NCH8; t += nw) {
        const int n0 = t * 8;
        GATHER_G8(gin)
        half8 ov;
        ov[0] = (half_t)acc0; ov[1] = (half_t)acc1;
        ov[2] = (half_t)acc2; ov[3] = (half_t)acc3;
        ov[4] = (half_t)acc4; ov[5] = (half_t)acc5;
        ov[6] = (half_t)acc6; ov[7] = (half_t)acc7;
        *(half8*)(sout + (size_t)n * 64 + sub * 8) = ov;
    }
}

// ---------------- k_mm2: g2 = (relu(dinv*s + b1) @ W2) * dinv ----------------

__global__ __launch_bounds__(256) void k_mm2(
    const float* __restrict__ W2, const float* __restrict__ b1,
    const float* __restrict__ dinv,
    const half_t* __restrict__ s, half_t* __restrict__ g)
{
    const int lane = threadIdx.x & 63;
    const int lg = lane >> 4, cl = lane & 15;
    const int wid = blockIdx.x * (blockDim.x >> 6) + (threadIdx.x >> 6);
    const int nw  = gridDim.x * (blockDim.x >> 6);

    half8 bf[2][4];
    build_bfrags(W2, lg, cl, bf);
    float bias0[8], bias1[8];
#pragma unroll
    for (int j = 0; j < 8; ++j) {
        bias0[j] = b1[8 * lg + j];
        bias1[j] = b1[32 + 8 * lg + j];
    }
    const f32x4 zacc = {0.f, 0.f, 0.f, 0.f};

    for (int t = wid; t < NGROUPS; t += nw) {
        const int n0 = t * 16;
        const int na = n0 + cl;
        const float dna = dinv[na];
        half8 s0 = *(const half8*)(s + (size_t)na * 64 + 8 * lg);
        half8 s1 = *(const half8*)(s + (size_t)na * 64 + 32 + 8 * lg);
        half8 a0, a1;
#pragma unroll
        for (int j = 0; j < 8; ++j) {
            a0[j] = (half_t)fmaxf(fmaf(dna, (float)s0[j], bias0[j]), 0.0f);
            a1[j] = (half_t)fmaxf(fmaf(dna, (float)s1[j], bias1[j]), 0.0f);
        }
        f32x4 acc[4];
#pragma unroll
        for (int c = 0; c < 4; ++c) {
            acc[c] = __builtin_amdgcn_mfma_f32_16x16x32_f16(a0, bf[0][c], zacc, 0, 0, 0);
            acc[c] = __builtin_amdgcn_mfma_f32_16x16x32_f16(a1, bf[1][c], acc[c], 0, 0, 0);
        }
#pragma unroll
        for (int r = 0; r < 4; ++r) {
            const int nd = n0 + lg * 4 + r;
            const float dn = dinv[nd];
            half4 hv;
#pragma unroll
            for (int c = 0; c < 4; ++c) hv[c] = (half_t)(acc[c][r] * dn);
            *(half4*)(g + (size_t)nd * 64 + 4 * cl) = hv;
        }
    }
}

// ---------------- gather(g2) + relu + Wp-dot fused -> pscore ----------------

__global__ __launch_bounds__(256) void k_gather_ps(
    const int* __restrict__ off, const int* __restrict__ csr,
    const float* __restrict__ b2, const float* __restrict__ Wp,
    const float* __restrict__ dinv,
    const half_t* __restrict__ g2, float* __restrict__ pscore)
{
    const int lane = threadIdx.x & 63;
    const int gi = lane >> 3;
    const int sub = lane & 7;
    const int wid = blockIdx.x * (blockDim.x >> 6) + (threadIdx.x >> 6);
    const int nw  = gridDim.x * (blockDim.x >> 6);

    float bb[8], wpu[8], wpi[8];
#pragma unroll
    for (int k = 0; k < 8; ++k) {
        bb[k]  = b2[sub * 8 + k];
        wpu[k] = Wp[sub * 8 + k];
        wpi[k] = Wp[64 + sub * 8 + k];
    }

    for (int t = wid; t < NCH8; t += nw) {
        const int n0 = t * 8;
        GATHER_G8(g2)

        const bool isu = (n0 < NUSERS);     // NUSERS%8==0: chunk uniform
        const float dn = dinv[n];
        float v = 0.0f;
#define PS_ACC(K, A) {                                                      \
        float w_ = isu ? wpu[K] : wpi[K];                                   \
        float x_ = fmaxf(fmaf(dn, (A), bb[K]), 0.0f);                       \
        v = fmaf(x_, w_, v); }
        PS_ACC(0, acc0) PS_ACC(1, acc1) PS_ACC(2, acc2) PS_ACC(3, acc3)
        PS_ACC(4, acc4) PS_ACC(5, acc5) PS_ACC(6, acc6) PS_ACC(7, acc7)
#undef PS_ACC
        v += __shfl_xor(v, 1, 64);
        v += __shfl_xor(v, 2, 64);
        v += __shfl_xor(v, 4, 64);
        if (sub == 0) pscore[n] = v;
    }
}

__global__ void k_pairs(const int* __restrict__ user_ids, const int* __restrict__ item_ids,
                        const float* __restrict__ pscore, const float* __restrict__ bp,
                        float* __restrict__ out)
{
    int b = blockIdx.x * blockDim.x + threadIdx.x;
    if (b < NUSERS)
        out[b] = pscore[user_ids[b]] + pscore[NUSERS + item_ids[b]] + bp[0];
}

// ---------------- launch ----------------
// Workspace layout (byte-exact):
//   deg/cursor :          0 ..   2,000,000   (reused as pscore after k_place)
//   dinv       :  2,000,000 ..   4,000,000
//   offsets    :  4,000,000 ..   6,000,004   (NNODES+1 ints)
//   partials   :  6,000,128 ..   6,007,944
//   csr_src    :  6,008,000 ..  10,808,000
//   bufA       : 10,808,064 ..  74,808,064   (NNODES*64 fp16)  g1, then g2
//   bufB       : 74,808,064 .. 138,808,064   s1

extern "C" void kernel_launch(void* const* d_in, const int* in_sizes, int n_in,
                              void* d_out, int out_size, void* d_ws, size_t ws_size,
                              hipStream_t stream)
{
    const float* user_table = (const float*)d_in[0];
    const float* item_table = (const float*)d_in[1];
    const float* W1 = (const float*)d_in[2];
    const float* b1 = (const float*)d_in[3];
    const float* W2 = (const float*)d_in[4];
    const float* b2 = (const float*)d_in[5];
    const float* Wp = (const float*)d_in[6];
    const float* bp = (const float*)d_in[7];
    const int* edge = (const int*)d_in[8];
    const int* uid  = (const int*)d_in[9];
    const int* iid  = (const int*)d_in[10];
    float* out = (float*)d_out;

    const int* src = edge;
    const int* dst = edge + NEDGES;

    char* ws = (char*)d_ws;
    int*    deg      = (int*)   (ws + 0);
    float*  dinv     = (float*) (ws + 2000000);
    int*    offsets  = (int*)   (ws + 4000000);
    int*    partials = (int*)   (ws + 6000128);
    int*    csr_src  = (int*)   (ws + 6008000);
    half_t* bufA     = (half_t*)(ws + 10808064);
    half_t* bufB     = (half_t*)(ws + 74808064);
    float*  pscore   = (float*) (ws + 0);        // aliases deg (dead after k_place)

    k_zero_deg     <<<NBLK, 256, 0, stream>>>(deg);
    k_count_deg    <<<(NEDGES + 255) / 256, 256, 0, stream>>>(dst, deg);
    k_dinv         <<<NBLK, 256, 0, stream>>>(deg, dinv);
    k_block_sums   <<<NBLK, 256, 0, stream>>>(deg, partials);
    k_scan_partials<<<1, 256, 0, stream>>>(partials);
    k_scan_blocks  <<<NBLK, 256, 0, stream>>>(partials, deg, offsets);
    k_place        <<<(NEDGES + 255) / 256, 256, 0, stream>>>(src, dst, deg, csr_src);

    k_mm1      <<<2048, 256, 0, stream>>>(user_table, item_table, uid, iid, W1, dinv, bufA);
    k_gather   <<<2048, 256, 0, stream>>>(offsets, csr_src, bufA, bufB);
    k_mm2      <<<2048, 256, 0, stream>>>(W2, b1, dinv, bufB, bufA);
    k_gather_ps<<<2048, 256, 0, stream>>>(offsets, csr_src, b2, Wp, dinv, bufA, pscore);
    k_pairs    <<<(NUSERS + 255) / 256, 256, 0, stream>>>(uid, iid, pscore, bp, out);
}

// Round 12
// 204.529 us; speedup vs baseline: 2.7350x; 1.4845x over previous
//
#include <hip/hip_runtime.h>

#define NUSERS 250000
#define NITEMS 250000
#define NNODES 500000
#define NEDGES 1200000
#define NGROUPS (NNODES/16)  // 31250
#define NCH8   (NNODES/8)    // 62500

#define NB     245           // buckets: dst>>11, 2048 nodes each (last: 288)
#define BCAP   6144          // per-bucket capacity (mean 4898, +17 sigma)
#define SEGE   8192          // edges per phase-A block
#define NBLKA  147           // ceil(NEDGES/SEGE)

typedef _Float16 half_t;
typedef _Float16 half8 __attribute__((ext_vector_type(8)));
typedef _Float16 half4 __attribute__((ext_vector_type(4)));
typedef float    f32x4 __attribute__((ext_vector_type(4)));

// ---------------- CSR build: two-level LDS counting sort ----------------

__global__ void k_zero_gc(int* __restrict__ gc) {
    int t = threadIdx.x;
    if (t < NB) gc[t] = 0;
}

// Phase A: bin edges into 245 coarse buckets with LDS staging; contiguous flush.
__global__ __launch_bounds__(256) void k_bucketA(
    const int* __restrict__ src, const int* __restrict__ dst,
    int* __restrict__ gcursor, unsigned int* __restrict__ gbuf)
{
    __shared__ int ecnt[256];
    __shared__ int ebase[256];
    __shared__ int ecur[256];
    __shared__ int gres[256];
    __shared__ unsigned int stage[SEGE];
    __shared__ unsigned char stb[SEGE];

    const int t = threadIdx.x;
    const int e0 = blockIdx.x * SEGE;
    const int ecount = min(SEGE, NEDGES - e0);

    ecnt[t] = 0;
    __syncthreads();
    for (int k = t; k < ecount; k += 256)
        atomicAdd(&ecnt[dst[e0 + k] >> 11], 1);
    __syncthreads();

    const int v = ecnt[t];
    ebase[t] = v; __syncthreads();
    for (int d = 1; d < 256; d <<= 1) {
        int x = (t >= d) ? ebase[t - d] : 0;
        __syncthreads();
        ebase[t] += x;
        __syncthreads();
    }
    const int excl = ebase[t] - v;
    __syncthreads();
    ebase[t] = excl;
    ecur[t]  = excl;
    if (t < NB && v > 0) gres[t] = atomicAdd(&gcursor[t], v);
    __syncthreads();

    for (int k = t; k < ecount; k += 256) {
        const int s  = src[e0 + k];
        const int d2 = dst[e0 + k];
        const int b  = d2 >> 11;
        const int p  = atomicAdd(&ecur[b], 1);
        stage[p] = ((unsigned int)s << 11) | (unsigned int)(d2 & 2047);
        stb[p]   = (unsigned char)b;
    }
    __syncthreads();

    for (int s = t; s < ecount; s += 256) {
        const int b = stb[s];
        gbuf[(size_t)b * BCAP + gres[b] + (s - ebase[s >= 0 ? b : 0])] = stage[s];
    }
}

// exclusive scan of the 245 bucket counts -> csr base per bucket
__global__ __launch_bounds__(256) void k_scan_buckets(const int* __restrict__ gcursor,
                                                      int* __restrict__ bbase)
{
    __shared__ int sm[256];
    const int t = threadIdx.x;
    const int v = (t < NB) ? gcursor[t] : 0;
    sm[t] = v; __syncthreads();
    for (int d = 1; d < 256; d <<= 1) {
        int x = (t >= d) ? sm[t - d] : 0;
        __syncthreads();
        sm[t] += x;
        __syncthreads();
    }
    if (t < NB) bbase[t] = sm[t] - v;
}

// Phase B: per bucket -> dinv, offsets, csr (LDS histogram/scan/place, coalesced out)
__global__ __launch_bounds__(256) void k_bucketB(
    const int* __restrict__ gcursor, const int* __restrict__ bbase,
    const unsigned int* __restrict__ gbuf,
    float* __restrict__ dinv, int* __restrict__ offsets, int* __restrict__ csr)
{
    __shared__ int hist[2048];
    __shared__ int cur[2048];
    __shared__ int psum[256];
    __shared__ int lcsr[BCAP];      // 8+8+1+24 = 41 KB LDS

    const int t = threadIdx.x;
    const int b = blockIdx.x;
    const int cnt = gcursor[b];
    const int nbase = b << 11;
    const int nb = min(2048, NNODES - nbase);
    const unsigned int* gb0 = gbuf + (size_t)b * BCAP;
    const int cbase = bbase[b];

    for (int i = t; i < 2048; i += 256) hist[i] = 0;
    __syncthreads();
    for (int s = t; s < cnt; s += 256)
        atomicAdd(&hist[gb0[s] & 2047], 1);
    __syncthreads();

    // dinv straight from histogram (self-loop adds 1)
    for (int i = t; i < nb; i += 256)
        dinv[nbase + i] = 1.0f / sqrtf((float)(hist[i] + 1));

    // exclusive scan of hist -> cur + global offsets
    int loc[8]; int ssum = 0;
#pragma unroll
    for (int k = 0; k < 8; ++k) { loc[k] = hist[t * 8 + k]; ssum += loc[k]; }
    psum[t] = ssum; __syncthreads();
    for (int d = 1; d < 256; d <<= 1) {
        int x = (t >= d) ? psum[t - d] : 0;
        __syncthreads();
        psum[t] += x;
        __syncthreads();
    }
    int run = psum[t] - ssum;
#pragma unroll
    for (int k = 0; k < 8; ++k) {
        const int i = t * 8 + k;
        if (i < nb) offsets[nbase + i] = cbase + run;
        cur[i] = run;
        run += loc[k];
    }
    __syncthreads();
    if (b == NB - 1 && t == 0) offsets[NNODES] = cbase + cnt;

    // place into LDS csr slice, then coalesced flush
    for (int s = t; s < cnt; s += 256) {
        const unsigned int pk = gb0[s];
        const int p = atomicAdd(&cur[pk & 2047], 1);
        lcsr[p] = (int)(pk >> 11);
    }
    __syncthreads();
    for (int s = t; s < cnt; s += 256)
        csr[cbase + s] = lcsr[s];
}

// ---------------- MFMA helpers ----------------
// A: lane holds row (lane&15), k = 32q + 8*(lane>>4) + j
// B: lane holds col-slot (lane&15), same k formula; out-feature = 4*(lane&15)+c
// C/D: node = n0 + (lane>>4)*4 + r, feat = 4*(lane&15)+c

__device__ __forceinline__ void build_bfrags(const float* __restrict__ W,
                                             int lg, int cl, half8 bf[2][4]) {
#pragma unroll
    for (int q = 0; q < 2; ++q)
#pragma unroll
        for (int c = 0; c < 4; ++c) {
            half8 v;
#pragma unroll
            for (int j = 0; j < 8; ++j)
                v[j] = (half_t)W[(32 * q + 8 * lg + j) * 64 + 4 * cl + c];
            bf[q][c] = v;
        }
}

// ---------------- k_mm1: g1 = (gather(emb) @ W1) * dinv  [fp16 out] ----------------

__global__ __launch_bounds__(256) void k_mm1(
    const float* __restrict__ user_table, const float* __restrict__ item_table,
    const int* __restrict__ uid, const int* __restrict__ iid,
    const float* __restrict__ W1, const float* __restrict__ dinv,
    half_t* __restrict__ g)
{
    const int lane = threadIdx.x & 63;
    const int lg = lane >> 4, cl = lane & 15;
    const int wid = blockIdx.x * (blockDim.x >> 6) + (threadIdx.x >> 6);
    const int nw  = gridDim.x * (blockDim.x >> 6);

    half8 bf[2][4];
    build_bfrags(W1, lg, cl, bf);
    const f32x4 zacc = {0.f, 0.f, 0.f, 0.f};

    for (int t = wid; t < NGROUPS; t += nw) {
        const int n0 = t * 16;
        const int na = n0 + cl;                    // NUSERS%16==0: tiles never straddle
        const float* p = (na < NUSERS)
            ? user_table + (size_t)uid[na] * 64
            : item_table + (size_t)iid[na - NUSERS] * 64;
        f32x4 u0 = *(const f32x4*)(p + 8 * lg);
        f32x4 u1 = *(const f32x4*)(p + 8 * lg + 4);
        f32x4 u2 = *(const f32x4*)(p + 8 * lg + 32);
        f32x4 u3 = *(const f32x4*)(p + 8 * lg + 36);
        half8 a0, a1;
#pragma unroll
        for (int j = 0; j < 4; ++j) {
            a0[j] = (half_t)u0[j]; a0[4 + j] = (half_t)u1[j];
            a1[j] = (half_t)u2[j]; a1[4 + j] = (half_t)u3[j];
        }
        f32x4 acc[4];
#pragma unroll
        for (int c = 0; c < 4; ++c) {
            acc[c] = __builtin_amdgcn_mfma_f32_16x16x32_f16(a0, bf[0][c], zacc, 0, 0, 0);
            acc[c] = __builtin_amdgcn_mfma_f32_16x16x32_f16(a1, bf[1][c], acc[c], 0, 0, 0);
        }
#pragma unroll
        for (int r = 0; r < 4; ++r) {
            const int nd = n0 + lg * 4 + r;
            const float dn = dinv[nd];
            half4 hv;
#pragma unroll
            for (int c = 0; c < 4; ++c) hv[c] = (half_t)(acc[c][r] * dn);
            *(half4*)(g + (size_t)nd * 64 + 4 * cl) = hv;
        }
    }
}

// ---------------- group-per-node gather ----------------
// 8-lane group owns one node; lane covers 8 features (16 B). One wave step
// processes 8 edges with ONE row-load instruction. No routing, no cross-group
// reduction. Loop trip = wave-max degree; invalid steps are masked by a 0/1
// multiplier on a safe csr[0] load.

#define GATHER_G8(gin)                                                        \
    const int n  = n0 + gi;                                                   \
    const int eb = off[n];                                                    \
    const int deg = off[n + 1] - eb;                                          \
    float acc0, acc1, acc2, acc3, acc4, acc5, acc6, acc7;                     \
    {                                                                         \
        half8 sv = *(const half8*)(gin + (size_t)n * 64 + sub * 8);           \
        acc0 = (float)sv[0]; acc1 = (float)sv[1];                             \
        acc2 = (float)sv[2]; acc3 = (float)sv[3];                             \
        acc4 = (float)sv[4]; acc5 = (float)sv[5];                             \
        acc6 = (float)sv[6]; acc7 = (float)sv[7];                             \
    }                                                                         \
    int md = deg;                                                             \
    md = max(md, __shfl_xor(md, 8, 64));                                      \
    md = max(md, __shfl_xor(md, 16, 64));                                     \
    md = max(md, __shfl_xor(md, 32, 64));                                     \
    for (int sstep = 0; sstep < md; sstep += 2) {                             \
        const bool v0 = sstep < deg, v1 = sstep + 1 < deg;                    \
        const int p0 = csr[v0 ? eb + sstep : 0];                              \
        const int p1 = csr[v1 ? eb + sstep + 1 : 0];                          \
        const half8 r0 = *(const half8*)(gin + (size_t)p0 * 64 + sub * 8);    \
        const half8 r1 = *(const half8*)(gin + (size_t)p1 * 64 + sub * 8);    \
        const float m0 = v0 ? 1.0f : 0.0f;                                    \
        const float m1 = v1 ? 1.0f : 0.0f;                                    \
        acc0 = fmaf(m0, (float)r0[0], acc0); acc1 = fmaf(m0, (float)r0[1], acc1); \
        acc2 = fmaf(m0, (float)r0[2], acc2); acc3 = fmaf(m0, (float)r0[3], acc3); \
        acc4 = fmaf(m0, (float)r0[4], acc4); acc5 = fmaf(m0, (float)r0[5], acc5); \
        acc6 = fmaf(m0, (float)r0[6], acc6); acc7 = fmaf(m0, (float)r0[7], acc7); \
        acc0 = fmaf(m1, (float)r1[0], acc0); acc1 = fmaf(m1, (float)r1[1], acc1); \
        acc2 = fmaf(m1, (float)r1[2], acc2); acc3 = fmaf(m1, (float)r1[3], acc3); \
        acc4 = fmaf(m1, (float)r1[4], acc4); acc5 = fmaf(m1, (float)r1[5], acc5); \
        acc6 = fmaf(m1, (float)r1[6], acc6); acc7 = fmaf(m1, (float)r1[7], acc7); \
    }

// pure gather: s[n] = g[n] + sum_in g[src]   [fp16 out]
__global__ __launch_bounds__(256) void k_gather(
    const int* __restrict__ off, const int* __restrict__ csr,
    const half_t* __restrict__ gin, half_t* __restrict__ sout)
{
    const int lane = threadIdx.x & 63;
    const int gi = lane >> 3;       // group = node slot 0..7
    const int sub = lane & 7;       // feature octet
    const int wid = blockIdx.x * (blockDim.x >> 6) + (threadIdx.x >> 6);
    const int nw  = gridDim.x * (blockDim.x >> 6);

    for (int t = wid; t < NCH8; t += nw) {
        const int n0 = t * 8;
        GATHER_G8(gin)
        half8 ov;
        ov[0] = (half_t)acc0; ov[1] = (half_t)acc1;
        ov[2] = (half_t)acc2; ov[3] = (half_t)acc3;
        ov[4] = (half_t)acc4; ov[5] = (half_t)acc5;
        ov[6] = (half_t)acc6; ov[7] = (half_t)acc7;
        *(half8*)(sout + (size_t)n * 64 + sub * 8) = ov;
    }
}

// ---------------- k_mm2: g2 = (relu(dinv*s + b1) @ W2) * dinv ----------------

__global__ __launch_bounds__(256) void k_mm2(
    const float* __restrict__ W2, const float* __restrict__ b1,
    const float* __restrict__ dinv,
    const half_t* __restrict__ s, half_t* __restrict__ g)
{
    const int lane = threadIdx.x & 63;
    const int lg = lane >> 4, cl = lane & 15;
    const int wid = blockIdx.x * (blockDim.x >> 6) + (threadIdx.x >> 6);
    const int nw  = gridDim.x * (blockDim.x >> 6);

    half8 bf[2][4];
    build_bfrags(W2, lg, cl, bf);
    float bias0[8], bias1[8];
#pragma unroll
    for (int j = 0; j < 8; ++j) {
        bias0[j] = b1[8 * lg + j];
        bias1[j] = b1[32 + 8 * lg + j];
    }
    const f32x4 zacc = {0.f, 0.f, 0.f, 0.f};

    for (int t = wid; t < NGROUPS; t += nw) {
        const int n0 = t * 16;
        const int na = n0 + cl;
        const float dna = dinv[na];
        half8 s0 = *(const half8*)(s + (size_t)na * 64 + 8 * lg);
        half8 s1 = *(const half8*)(s + (size_t)na * 64 + 32 + 8 * lg);
        half8 a0, a1;
#pragma unroll
        for (int j = 0; j < 8; ++j) {
            a0[j] = (half_t)fmaxf(fmaf(dna, (float)s0[j], bias0[j]), 0.0f);
            a1[j] = (half_t)fmaxf(fmaf(dna, (float)s1[j], bias1[j]), 0.0f);
        }
        f32x4 acc[4];
#pragma unroll
        for (int c = 0; c < 4; ++c) {
            acc[c] = __builtin_amdgcn_mfma_f32_16x16x32_f16(a0, bf[0][c], zacc, 0, 0, 0);
            acc[c] = __builtin_amdgcn_mfma_f32_16x16x32_f16(a1, bf[1][c], acc[c], 0, 0, 0);
        }
#pragma unroll
        for (int r = 0; r < 4; ++r) {
            const int nd = n0 + lg * 4 + r;
            const float dn = dinv[nd];
            half4 hv;
#pragma unroll
            for (int c = 0; c < 4; ++c) hv[c] = (half_t)(acc[c][r] * dn);
            *(half4*)(g + (size_t)nd * 64 + 4 * cl) = hv;
        }
    }
}

// ---------------- gather(g2) + relu + Wp-dot fused -> pscore ----------------

__global__ __launch_bounds__(256) void k_gather_ps(
    const int* __restrict__ off, const int* __restrict__ csr,
    const float* __restrict__ b2, const float* __restrict__ Wp,
    const float* __restrict__ dinv,
    const half_t* __restrict__ g2, float* __restrict__ pscore)
{
    const int lane = threadIdx.x & 63;
    const int gi = lane >> 3;
    const int sub = lane & 7;
    const int wid = blockIdx.x * (blockDim.x >> 6) + (threadIdx.x >> 6);
    const int nw  = gridDim.x * (blockDim.x >> 6);

    float bb[8], wpu[8], wpi[8];
#pragma unroll
    for (int k = 0; k < 8; ++k) {
        bb[k]  = b2[sub * 8 + k];
        wpu[k] = Wp[sub * 8 + k];
        wpi[k] = Wp[64 + sub * 8 + k];
    }

    for (int t = wid; t < NCH8; t += nw) {
        const int n0 = t * 8;
        GATHER_G8(g2)

        const bool isu = (n0 < NUSERS);     // NUSERS%8==0: chunk uniform
        const float dn = dinv[n];
        float v = 0.0f;
#define PS_ACC(K, A) {                                                      \
        float w_ = isu ? wpu[K] : wpi[K];                                   \
        float x_ = fmaxf(fmaf(dn, (A), bb[K]), 0.0f);                       \
        v = fmaf(x_, w_, v); }
        PS_ACC(0, acc0) PS_ACC(1, acc1) PS_ACC(2, acc2) PS_ACC(3, acc3)
        PS_ACC(4, acc4) PS_ACC(5, acc5) PS_ACC(6, acc6) PS_ACC(7, acc7)
#undef PS_ACC
        v += __shfl_xor(v, 1, 64);
        v += __shfl_xor(v, 2, 64);
        v += __shfl_xor(v, 4, 64);
        if (sub == 0) pscore[n] = v;
    }
}

__global__ void k_pairs(const int* __restrict__ user_ids, const int* __restrict__ item_ids,
                        const float* __restrict__ pscore, const float* __restrict__ bp,
                        float* __restrict__ out)
{
    int b = blockIdx.x * blockDim.x + threadIdx.x;
    if (b < NUSERS)
        out[b] = pscore[user_ids[b]] + pscore[NUSERS + item_ids[b]] + bp[0];
}

// ---------------- launch ----------------
// Workspace layout (byte-exact):
//   pscore     :          0 ..   2,000,000
//   dinv       :  2,000,000 ..   4,000,000
//   offsets    :  4,000,000 ..   6,000,004   (NNODES+1 ints)
//   bbase      :  6,000,128 ..   6,001,108   (NB ints)
//   gcursor    :  6,004,224 ..   6,005,204   (NB ints)
//   csr        :  6,008,000 ..  10,808,000   (NEDGES ints)
//   bufA       : 10,808,064 ..  74,808,064   (NNODES*64 fp16)  g1, then g2
//   bufB       : 74,808,064 .. 138,808,064   s1
//   gbuf       : aliases bufB (74,808,064 .. 80,829,184) — dead before k_gather

extern "C" void kernel_launch(void* const* d_in, const int* in_sizes, int n_in,
                              void* d_out, int out_size, void* d_ws, size_t ws_size,
                              hipStream_t stream)
{
    const float* user_table = (const float*)d_in[0];
    const float* item_table = (const float*)d_in[1];
    const float* W1 = (const float*)d_in[2];
    const float* b1 = (const float*)d_in[3];
    const float* W2 = (const float*)d_in[4];
    const float* b2 = (const float*)d_in[5];
    const float* Wp = (const float*)d_in[6];
    const float* bp = (const float*)d_in[7];
    const int* edge = (const int*)d_in[8];
    const int* uid  = (const int*)d_in[9];
    const int* iid  = (const int*)d_in[10];
    float* out = (float*)d_out;

    const int* src = edge;
    const int* dst = edge + NEDGES;

    char* ws = (char*)d_ws;
    float*        pscore   = (float*)       (ws + 0);
    float*        dinv     = (float*)       (ws + 2000000);
    int*          offsets  = (int*)         (ws + 4000000);
    int*          bbase    = (int*)         (ws + 6000128);
    int*          gcursor  = (int*)         (ws + 6004224);
    int*          csr      = (int*)         (ws + 6008000);
    half_t*       bufA     = (half_t*)      (ws + 10808064);
    half_t*       bufB     = (half_t*)      (ws + 74808064);
    unsigned int* gbuf     = (unsigned int*)(ws + 74808064);   // aliases bufB

    k_zero_gc     <<<1, 256, 0, stream>>>(gcursor);
    k_bucketA     <<<NBLKA, 256, 0, stream>>>(src, dst, gcursor, gbuf);
    k_scan_buckets<<<1, 256, 0, stream>>>(gcursor, bbase);
    k_bucketB     <<<NB, 256, 0, stream>>>(gcursor, bbase, gbuf, dinv, offsets, csr);

    k_mm1      <<<2048, 256, 0, stream>>>(user_table, item_table, uid, iid, W1, dinv, bufA);
    k_gather   <<<2048, 256, 0, stream>>>(offsets, csr, bufA, bufB);
    k_mm2      <<<2048, 256, 0, stream>>>(W2, b1, dinv, bufB, bufA);
    k_gather_ps<<<2048, 256, 0, stream>>>(offsets, csr, b2, Wp, dinv, bufA, pscore);
    k_pairs    <<<(NUSERS + 255) / 256, 256, 0, stream>>>(uid, iid, pscore, bp, out);
}

// Round 13
// 197.291 us; speedup vs baseline: 2.8353x; 1.0367x over previous
//
#include <hip/hip_runtime.h>

#define NUSERS 250000
#define NITEMS 250000
#define NNODES 500000
#define NEDGES 1200000
#define NGROUPS (NNODES/16)  // 31250
#define NCH8   (NNODES/8)    // 62500

#define NB     245           // buckets: dst>>11, 2048 nodes each (last: 288)
#define BCAP   6144          // per-bucket capacity (mean 4898, +17 sigma)
#define SEGE   8192          // edges per phase-A block
#define NBLKA  147           // ceil(NEDGES/SEGE)

typedef _Float16 half_t;
typedef _Float16 half8 __attribute__((ext_vector_type(8)));
typedef _Float16 half4 __attribute__((ext_vector_type(4)));
typedef float    f32x4 __attribute__((ext_vector_type(4)));

// ---------------- CSR build: two-level LDS counting sort ----------------

__global__ void k_zero_gc(int* __restrict__ gc) {
    int t = threadIdx.x;
    if (t < NB) gc[t] = 0;
}

// Phase A: bin edges into 245 coarse buckets with LDS staging; contiguous flush.
__global__ __launch_bounds__(256) void k_bucketA(
    const int* __restrict__ src, const int* __restrict__ dst,
    int* __restrict__ gcursor, unsigned int* __restrict__ gbuf)
{
    __shared__ int ecnt[256];
    __shared__ int ebase[256];
    __shared__ int ecur[256];
    __shared__ int gres[256];
    __shared__ unsigned int stage[SEGE];
    __shared__ unsigned char stb[SEGE];

    const int t = threadIdx.x;
    const int e0 = blockIdx.x * SEGE;
    const int ecount = min(SEGE, NEDGES - e0);

    ecnt[t] = 0;
    __syncthreads();
    for (int k = t; k < ecount; k += 256)
        atomicAdd(&ecnt[dst[e0 + k] >> 11], 1);
    __syncthreads();

    const int v = ecnt[t];
    ebase[t] = v; __syncthreads();
    for (int d = 1; d < 256; d <<= 1) {
        int x = (t >= d) ? ebase[t - d] : 0;
        __syncthreads();
        ebase[t] += x;
        __syncthreads();
    }
    const int excl = ebase[t] - v;
    __syncthreads();
    ebase[t] = excl;
    ecur[t]  = excl;
    if (t < NB && v > 0) gres[t] = atomicAdd(&gcursor[t], v);
    __syncthreads();

    for (int k = t; k < ecount; k += 256) {
        const int s  = src[e0 + k];
        const int d2 = dst[e0 + k];
        const int b  = d2 >> 11;
        const int p  = atomicAdd(&ecur[b], 1);
        stage[p] = ((unsigned int)s << 11) | (unsigned int)(d2 & 2047);
        stb[p]   = (unsigned char)b;
    }
    __syncthreads();

    for (int s = t; s < ecount; s += 256) {
        const int b = stb[s];
        gbuf[(size_t)b * BCAP + gres[b] + (s - ebase[b])] = stage[s];
    }
}

// exclusive scan of the 245 bucket counts -> csr base per bucket
__global__ __launch_bounds__(256) void k_scan_buckets(const int* __restrict__ gcursor,
                                                      int* __restrict__ bbase)
{
    __shared__ int sm[256];
    const int t = threadIdx.x;
    const int v = (t < NB) ? gcursor[t] : 0;
    sm[t] = v; __syncthreads();
    for (int d = 1; d < 256; d <<= 1) {
        int x = (t >= d) ? sm[t - d] : 0;
        __syncthreads();
        sm[t] += x;
        __syncthreads();
    }
    if (t < NB) bbase[t] = sm[t] - v;
}

// Phase B: per bucket -> dinv, offsets, csr (LDS histogram/scan/place, coalesced out)
__global__ __launch_bounds__(256) void k_bucketB(
    const int* __restrict__ gcursor, const int* __restrict__ bbase,
    const unsigned int* __restrict__ gbuf,
    float* __restrict__ dinv, int* __restrict__ offsets, int* __restrict__ csr)
{
    __shared__ int hist[2048];
    __shared__ int cur[2048];
    __shared__ int psum[256];
    __shared__ int lcsr[BCAP];      // 8+8+1+24 = 41 KB LDS

    const int t = threadIdx.x;
    const int b = blockIdx.x;
    const int cnt = gcursor[b];
    const int nbase = b << 11;
    const int nb = min(2048, NNODES - nbase);
    const unsigned int* gb0 = gbuf + (size_t)b * BCAP;
    const int cbase = bbase[b];

    for (int i = t; i < 2048; i += 256) hist[i] = 0;
    __syncthreads();
    for (int s = t; s < cnt; s += 256)
        atomicAdd(&hist[gb0[s] & 2047], 1);
    __syncthreads();

    // dinv straight from histogram (self-loop adds 1)
    for (int i = t; i < nb; i += 256)
        dinv[nbase + i] = 1.0f / sqrtf((float)(hist[i] + 1));

    // exclusive scan of hist -> cur + global offsets
    int loc[8]; int ssum = 0;
#pragma unroll
    for (int k = 0; k < 8; ++k) { loc[k] = hist[t * 8 + k]; ssum += loc[k]; }
    psum[t] = ssum; __syncthreads();
    for (int d = 1; d < 256; d <<= 1) {
        int x = (t >= d) ? psum[t - d] : 0;
        __syncthreads();
        psum[t] += x;
        __syncthreads();
    }
    int run = psum[t] - ssum;
#pragma unroll
    for (int k = 0; k < 8; ++k) {
        const int i = t * 8 + k;
        if (i < nb) offsets[nbase + i] = cbase + run;
        cur[i] = run;
        run += loc[k];
    }
    __syncthreads();
    if (b == NB - 1 && t == 0) offsets[NNODES] = cbase + cnt;

    // place into LDS csr slice, then coalesced flush
    for (int s = t; s < cnt; s += 256) {
        const unsigned int pk = gb0[s];
        const int p = atomicAdd(&cur[pk & 2047], 1);
        lcsr[p] = (int)(pk >> 11);
    }
    __syncthreads();
    for (int s = t; s < cnt; s += 256)
        csr[cbase + s] = lcsr[s];
}

// ---------------- MFMA helpers ----------------
// A: lane holds row (lane&15), k = 32q + 8*(lane>>4) + j
// B: lane holds col-slot (lane&15), same k formula; out-feature = 4*(lane&15)+c
// C/D: node = n0 + (lane>>4)*4 + r, feat = 4*(lane&15)+c

__device__ __forceinline__ void build_bfrags(const float* __restrict__ W,
                                             int lg, int cl, half8 bf[2][4]) {
#pragma unroll
    for (int q = 0; q < 2; ++q)
#pragma unroll
        for (int c = 0; c < 4; ++c) {
            half8 v;
#pragma unroll
            for (int j = 0; j < 8; ++j)
                v[j] = (half_t)W[(32 * q + 8 * lg + j) * 64 + 4 * cl + c];
            bf[q][c] = v;
        }
}

// ---------------- k_mm1: g1 = (gather(emb) @ W1) * dinv  [fp16 out] ----------------
// 2-tile software pipeline: tile t+1's row loads are issued before tile t's
// convert/MFMA/store, hiding the random 256B row-load latency under compute.

__global__ __launch_bounds__(256) void k_mm1(
    const float* __restrict__ user_table, const float* __restrict__ item_table,
    const int* __restrict__ uid, const int* __restrict__ iid,
    const float* __restrict__ W1, const float* __restrict__ dinv,
    half_t* __restrict__ g)
{
    const int lane = threadIdx.x & 63;
    const int lg = lane >> 4, cl = lane & 15;
    const int wid = blockIdx.x * (blockDim.x >> 6) + (threadIdx.x >> 6);
    const int nw  = gridDim.x * (blockDim.x >> 6);

    half8 bf[2][4];
    build_bfrags(W1, lg, cl, bf);
    const f32x4 zacc = {0.f, 0.f, 0.f, 0.f};

    int t = wid;
    f32x4 u0, u1, u2, u3;
    if (t < NGROUPS) {
        const int na = t * 16 + cl;                // NUSERS%16==0: tiles never straddle
        const float* p = (na < NUSERS)
            ? user_table + (size_t)uid[na] * 64
            : item_table + (size_t)iid[na - NUSERS] * 64;
        u0 = *(const f32x4*)(p + 8 * lg);
        u1 = *(const f32x4*)(p + 8 * lg + 4);
        u2 = *(const f32x4*)(p + 8 * lg + 32);
        u3 = *(const f32x4*)(p + 8 * lg + 36);
    }
    while (t < NGROUPS) {
        const int tn = t + nw;
        const int tl = (tn < NGROUPS) ? tn : t;    // safe reload on last iter
        const int nb2 = tl * 16 + cl;
        const float* pn = (nb2 < NUSERS)
            ? user_table + (size_t)uid[nb2] * 64
            : item_table + (size_t)iid[nb2 - NUSERS] * 64;
        f32x4 v0 = *(const f32x4*)(pn + 8 * lg);
        f32x4 v1 = *(const f32x4*)(pn + 8 * lg + 4);
        f32x4 v2 = *(const f32x4*)(pn + 8 * lg + 32);
        f32x4 v3 = *(const f32x4*)(pn + 8 * lg + 36);

        const int n0 = t * 16;
        half8 a0, a1;
#pragma unroll
        for (int j = 0; j < 4; ++j) {
            a0[j] = (half_t)u0[j]; a0[4 + j] = (half_t)u1[j];
            a1[j] = (half_t)u2[j]; a1[4 + j] = (half_t)u3[j];
        }
        f32x4 acc[4];
#pragma unroll
        for (int c = 0; c < 4; ++c) {
            acc[c] = __builtin_amdgcn_mfma_f32_16x16x32_f16(a0, bf[0][c], zacc, 0, 0, 0);
            acc[c] = __builtin_amdgcn_mfma_f32_16x16x32_f16(a1, bf[1][c], acc[c], 0, 0, 0);
        }
#pragma unroll
        for (int r = 0; r < 4; ++r) {
            const int nd = n0 + lg * 4 + r;
            const float dn = dinv[nd];
            half4 hv;
#pragma unroll
            for (int c = 0; c < 4; ++c) hv[c] = (half_t)(acc[c][r] * dn);
            *(half4*)(g + (size_t)nd * 64 + 4 * cl) = hv;
        }
        u0 = v0; u1 = v1; u2 = v2; u3 = v3;
        t = tn;
    }
}

// ---------------- group-per-node gather ----------------
// 8-lane group owns one node; lane covers 8 features (16 B). One wave step now
// processes up to 4 edges/node with FOUR row-load instructions in flight.
// Invalid steps masked by 0/1 multiplier on a safe csr[0] load.

#define GATHER_G8(gin)                                                        \
    const int n  = n0 + gi;                                                   \
    const int eb = off[n];                                                    \
    const int deg = off[n + 1] - eb;                                          \
    float acc0, acc1, acc2, acc3, acc4, acc5, acc6, acc7;                     \
    {                                                                         \
        half8 sv = *(const half8*)(gin + (size_t)n * 64 + sub * 8);           \
        acc0 = (float)sv[0]; acc1 = (float)sv[1];                             \
        acc2 = (float)sv[2]; acc3 = (float)sv[3];                             \
        acc4 = (float)sv[4]; acc5 = (float)sv[5];                             \
        acc6 = (float)sv[6]; acc7 = (float)sv[7];                             \
    }                                                                         \
    int md = deg;                                                             \
    md = max(md, __shfl_xor(md, 8, 64));                                      \
    md = max(md, __shfl_xor(md, 16, 64));                                     \
    md = max(md, __shfl_xor(md, 32, 64));                                     \
    for (int sstep = 0; sstep < md; sstep += 4) {                             \
        const bool v0 = sstep < deg,     v1 = sstep + 1 < deg;                \
        const bool v2 = sstep + 2 < deg, v3 = sstep + 3 < deg;                \
        const int p0 = csr[v0 ? eb + sstep     : 0];                          \
        const int p1 = csr[v1 ? eb + sstep + 1 : 0];                          \
        const int p2 = csr[v2 ? eb + sstep + 2 : 0];                          \
        const int p3 = csr[v3 ? eb + sstep + 3 : 0];                          \
        const half8 r0 = *(const half8*)(gin + (size_t)p0 * 64 + sub * 8);    \
        const half8 r1 = *(const half8*)(gin + (size_t)p1 * 64 + sub * 8);    \
        const half8 r2 = *(const half8*)(gin + (size_t)p2 * 64 + sub * 8);    \
        const half8 r3 = *(const half8*)(gin + (size_t)p3 * 64 + sub * 8);    \
        const float m0 = v0 ? 1.0f : 0.0f;                                    \
        const float m1 = v1 ? 1.0f : 0.0f;                                    \
        const float m2 = v2 ? 1.0f : 0.0f;                                    \
        const float m3 = v3 ? 1.0f : 0.0f;                                    \
        acc0 = fmaf(m0, (float)r0[0], acc0); acc1 = fmaf(m0, (float)r0[1], acc1); \
        acc2 = fmaf(m0, (float)r0[2], acc2); acc3 = fmaf(m0, (float)r0[3], acc3); \
        acc4 = fmaf(m0, (float)r0[4], acc4); acc5 = fmaf(m0, (float)r0[5], acc5); \
        acc6 = fmaf(m0, (float)r0[6], acc6); acc7 = fmaf(m0, (float)r0[7], acc7); \
        acc0 = fmaf(m1, (float)r1[0], acc0); acc1 = fmaf(m1, (float)r1[1], acc1); \
        acc2 = fmaf(m1, (float)r1[2], acc2); acc3 = fmaf(m1, (float)r1[3], acc3); \
        acc4 = fmaf(m1, (float)r1[4], acc4); acc5 = fmaf(m1, (float)r1[5], acc5); \
        acc6 = fmaf(m1, (float)r1[6], acc6); acc7 = fmaf(m1, (float)r1[7], acc7); \
        acc0 = fmaf(m2, (float)r2[0], acc0); acc1 = fmaf(m2, (float)r2[1], acc1); \
        acc2 = fmaf(m2, (float)r2[2], acc2); acc3 = fmaf(m2, (float)r2[3], acc3); \
        acc4 = fmaf(m2, (float)r2[4], acc4); acc5 = fmaf(m2, (float)r2[5], acc5); \
        acc6 = fmaf(m2, (float)r2[6], acc6); acc7 = fmaf(m2, (float)r2[7], acc7); \
        acc0 = fmaf(m3, (float)r3[0], acc0); acc1 = fmaf(m3, (float)r3[1], acc1); \
        acc2 = fmaf(m3, (float)r3[2], acc2); acc3 = fmaf(m3, (float)r3[3], acc3); \
        acc4 = fmaf(m3, (float)r3[4], acc4); acc5 = fmaf(m3, (float)r3[5], acc5); \
        acc6 = fmaf(m3, (float)r3[6], acc6); acc7 = fmaf(m3, (float)r3[7], acc7); \
    }

// pure gather: s[n] = g[n] + sum_in g[src]   [fp16 out]
__global__ __launch_bounds__(256) void k_gather(
    const int* __restrict__ off, const int* __restrict__ csr,
    const half_t* __restrict__ gin, half_t* __restrict__ sout)
{
    const int lane = threadIdx.x & 63;
    const int gi = lane >> 3;       // group = node slot 0..7
    const int sub = lane & 7;       // feature octet
    const int wid = blockIdx.x * (blockDim.x >> 6) + (threadIdx.x >> 6);
    const int nw  = gridDim.x * (blockDim.x >> 6);

    for (int t = wid; t < NCH8; t += nw) {
        const int n0 = t * 8;
        GATHER_G8(gin)
        half8 ov;
        ov[0] = (half_t)acc0; ov[1] = (half_t)acc1;
        ov[2] = (half_t)acc2; ov[3] = (half_t)acc3;
        ov[4] = (half_t)acc4; ov[5] = (half_t)acc5;
        ov[6] = (half_t)acc6; ov[7] = (half_t)acc7;
        *(half8*)(sout + (size_t)n * 64 + sub * 8) = ov;
    }
}

// ---------------- k_mm2: g2 = (relu(dinv*s + b1) @ W2) * dinv ----------------

__global__ __launch_bounds__(256) void k_mm2(
    const float* __restrict__ W2, const float* __restrict__ b1,
    const float* __restrict__ dinv,
    const half_t* __restrict__ s, half_t* __restrict__ g)
{
    const int lane = threadIdx.x & 63;
    const int lg = lane >> 4, cl = lane & 15;
    const int wid = blockIdx.x * (blockDim.x >> 6) + (threadIdx.x >> 6);
    const int nw  = gridDim.x * (blockDim.x >> 6);

    half8 bf[2][4];
    build_bfrags(W2, lg, cl, bf);
    float bias0[8], bias1[8];
#pragma unroll
    for (int j = 0; j < 8; ++j) {
        bias0[j] = b1[8 * lg + j];
        bias1[j] = b1[32 + 8 * lg + j];
    }
    const f32x4 zacc = {0.f, 0.f, 0.f, 0.f};

    for (int t = wid; t < NGROUPS; t += nw) {
        const int n0 = t * 16;
        const int na = n0 + cl;
        const float dna = dinv[na];
        half8 s0 = *(const half8*)(s + (size_t)na * 64 + 8 * lg);
        half8 s1 = *(const half8*)(s + (size_t)na * 64 + 32 + 8 * lg);
        half8 a0, a1;
#pragma unroll
        for (int j = 0; j < 8; ++j) {
            a0[j] = (half_t)fmaxf(fmaf(dna, (float)s0[j], bias0[j]), 0.0f);
            a1[j] = (half_t)fmaxf(fmaf(dna, (float)s1[j], bias1[j]), 0.0f);
        }
        f32x4 acc[4];
#pragma unroll
        for (int c = 0; c < 4; ++c) {
            acc[c] = __builtin_amdgcn_mfma_f32_16x16x32_f16(a0, bf[0][c], zacc, 0, 0, 0);
            acc[c] = __builtin_amdgcn_mfma_f32_16x16x32_f16(a1, bf[1][c], acc[c], 0, 0, 0);
        }
#pragma unroll
        for (int r = 0; r < 4; ++r) {
            const int nd = n0 + lg * 4 + r;
            const float dn = dinv[nd];
            half4 hv;
#pragma unroll
            for (int c = 0; c < 4; ++c) hv[c] = (half_t)(acc[c][r] * dn);
            *(half4*)(g + (size_t)nd * 64 + 4 * cl) = hv;
        }
    }
}

// ---------------- gather(g2) + relu + Wp-dot fused -> pscore ----------------

__global__ __launch_bounds__(256) void k_gather_ps(
    const int* __restrict__ off, const int* __restrict__ csr,
    const float* __restrict__ b2, const float* __restrict__ Wp,
    const float* __restrict__ dinv,
    const half_t* __restrict__ g2, float* __restrict__ pscore)
{
    const int lane = threadIdx.x & 63;
    const int gi = lane >> 3;
    const int sub = lane & 7;
    const int wid = blockIdx.x * (blockDim.x >> 6) + (threadIdx.x >> 6);
    const int nw  = gridDim.x * (blockDim.x >> 6);

    float bb[8], wpu[8], wpi[8];
#pragma unroll
    for (int k = 0; k < 8; ++k) {
        bb[k]  = b2[sub * 8 + k];
        wpu[k] = Wp[sub * 8 + k];
        wpi[k] = Wp[64 + sub * 8 + k];
    }

    for (int t = wid; t < NCH8; t += nw) {
        const int n0 = t * 8;
        GATHER_G8(g2)

        const bool isu = (n0 < NUSERS);     // NUSERS%8==0: chunk uniform
        const float dn = dinv[n];
        float v = 0.0f;
#define PS_ACC(K, A) {                                                      \
        float w_ = isu ? wpu[K] : wpi[K];                                   \
        float x_ = fmaxf(fmaf(dn, (A), bb[K]), 0.0f);                       \
        v = fmaf(x_, w_, v); }
        PS_ACC(0, acc0) PS_ACC(1, acc1) PS_ACC(2, acc2) PS_ACC(3, acc3)
        PS_ACC(4, acc4) PS_ACC(5, acc5) PS_ACC(6, acc6) PS_ACC(7, acc7)
#undef PS_ACC
        v += __shfl_xor(v, 1, 64);
        v += __shfl_xor(v, 2, 64);
        v += __shfl_xor(v, 4, 64);
        if (sub == 0) pscore[n] = v;
    }
}

__global__ void k_pairs(const int* __restrict__ user_ids, const int* __restrict__ item_ids,
                        const float* __restrict__ pscore, const float* __restrict__ bp,
                        float* __restrict__ out)
{
    int b = blockIdx.x * blockDim.x + threadIdx.x;
    if (b < NUSERS)
        out[b] = pscore[user_ids[b]] + pscore[NUSERS + item_ids[b]] + bp[0];
}

// ---------------- launch ----------------
// Workspace layout (byte-exact):
//   pscore     :          0 ..   2,000,000
//   dinv       :  2,000,000 ..   4,000,000
//   offsets    :  4,000,000 ..   6,000,004   (NNODES+1 ints)
//   bbase      :  6,000,128 ..   6,001,108   (NB ints)
//   gcursor    :  6,004,224 ..   6,005,204   (NB ints)
//   csr        :  6,008,000 ..  10,808,000   (NEDGES ints)
//   bufA       : 10,808,064 ..  74,808,064   (NNODES*64 fp16)  g1, then g2
//   bufB       : 74,808,064 .. 138,808,064   s1
//   gbuf       : aliases bufB (74,808,064 .. 80,829,184) — dead before k_gather

extern "C" void kernel_launch(void* const* d_in, const int* in_sizes, int n_in,
                              void* d_out, int out_size, void* d_ws, size_t ws_size,
                              hipStream_t stream)
{
    const float* user_table = (const float*)d_in[0];
    const float* item_table = (const float*)d_in[1];
    const float* W1 = (const float*)d_in[2];
    const float* b1 = (const float*)d_in[3];
    const float* W2 = (const float*)d_in[4];
    const float* b2 = (const float*)d_in[5];
    const float* Wp = (const float*)d_in[6];
    const float* bp = (const float*)d_in[7];
    const int* edge = (const int*)d_in[8];
    const int* uid  = (const int*)d_in[9];
    const int* iid  = (const int*)d_in[10];
    float* out = (float*)d_out;

    const int* src = edge;
    const int* dst = edge + NEDGES;

    char* ws = (char*)d_ws;
    float*        pscore   = (float*)       (ws + 0);
    float*        dinv     = (float*)       (ws + 2000000);
    int*          offsets  = (int*)         (ws + 4000000);
    int*          bbase    = (int*)         (ws + 6000128);
    int*          gcursor  = (int*)         (ws + 6004224);
    int*          csr      = (int*)         (ws + 6008000);
    half_t*       bufA     = (half_t*)      (ws + 10808064);
    half_t*       bufB     = (half_t*)      (ws + 74808064);
    unsigned int* gbuf     = (unsigned int*)(ws + 74808064);   // aliases bufB

    k_zero_gc     <<<1, 256, 0, stream>>>(gcursor);
    k_bucketA     <<<NBLKA, 256, 0, stream>>>(src, dst, gcursor, gbuf);
    k_scan_buckets<<<1, 256, 0, stream>>>(gcursor, bbase);
    k_bucketB     <<<NB, 256, 0, stream>>>(gcursor, bbase, gbuf, dinv, offsets, csr);

    k_mm1      <<<2048, 256, 0, stream>>>(user_table, item_table, uid, iid, W1, dinv, bufA);
    k_gather   <<<2048, 256, 0, stream>>>(offsets, csr, bufA, bufB);
    k_mm2      <<<2048, 256, 0, stream>>>(W2, b1, dinv, bufB, bufA);
    k_gather_ps<<<2048, 256, 0, stream>>>(offsets, csr, b2, Wp, dinv, bufA, pscore);
    k_pairs    <<<(NUSERS + 255) / 256, 256, 0, stream>>>(uid, iid, pscore, bp, out);
}